// Round 6
// baseline (650.819 us; speedup 1.0000x reference)
//
#include <hip/hip_runtime.h>
#include <hip/hip_bf16.h>

typedef __attribute__((ext_vector_type(8))) short bf16x8;
typedef __attribute__((ext_vector_type(4))) float f32x4;
typedef __hip_bfloat16 bf16;

#define DEV __device__ __forceinline__
DEV float sigmoidf_(float x) { return 1.0f / (1.0f + __expf(-x)); }
DEV float bf2f(bf16 v) { return __bfloat162float(v); }
DEV bf16  f2bf(float v) { return __float2bfloat16(v); }

typedef const __attribute__((address_space(1))) void* gptr_t;
typedef __attribute__((address_space(3))) void* lptr_t;

// ---------------------------------------------------------------------------
// bf16 MFMA GEMM (verified in R4): C = act(A @ W^T + bias)
// BM=128, BK=32, 4 waves 2x2, 16x16x32 MFMA, global_load_lds w/ pre-swizzled
// source (byte ^= (row&3)<<4 inside the 64-B BK-row).
// ---------------------------------------------------------------------------
template<int BN, int ACT, int OUTBF>
__global__ __launch_bounds__(256)
void gemm_mfma(const bf16* __restrict__ A, int lda,
               const bf16* __restrict__ W, int ldw,
               const float* __restrict__ bias,
               void* __restrict__ Cp, int ldc, int K)
{
    constexpr int BM = 128, BK = 32;
    constexpr int WN = BN / 2;
    constexpr int FM = 4, FN = WN / 16;
    constexpr int AITER = (BM * BK * 2) / (256 * 16);
    constexpr int BITER = (BN * BK * 2) / (256 * 16);

    __shared__ __align__(16) ushort As[BM * BK];
    __shared__ __align__(16) ushort Bs[BN * BK];

    const int tid = threadIdx.x;
    const int lane = tid & 63;
    const int wid = tid >> 6;
    const int wm = wid >> 1, wn = wid & 1;
    const long m0 = (long)blockIdx.y * BM;
    const long n0 = (long)blockIdx.x * BN;

    f32x4 acc[FM][FN] = {};

    int arow[AITER], acol[AITER];
#pragma unroll
    for (int it = 0; it < AITER; ++it) {
        int q = it * 256 + tid;
        int r = q >> 2;
        arow[it] = r;
        acol[it] = ((q & 3) * 16) ^ ((r & 3) << 4);
    }
    int brow[BITER], bcol[BITER];
#pragma unroll
    for (int it = 0; it < BITER; ++it) {
        int q = it * 256 + tid;
        int r = q >> 2;
        brow[it] = r;
        bcol[it] = ((q & 3) * 16) ^ ((r & 3) << 4);
    }

    const int fr = lane & 15, fq = lane >> 4;
    const int swz = (fr & 3) << 4;

    for (int k0 = 0; k0 < K; k0 += BK) {
#pragma unroll
        for (int it = 0; it < AITER; ++it) {
            const char* src = (const char*)A +
                ((size_t)(m0 + arow[it]) * lda + k0) * 2 + acol[it];
            __builtin_amdgcn_global_load_lds(
                (gptr_t)src,
                (lptr_t)((char*)As + (it * 256 + wid * 64) * 16), 16, 0, 0);
        }
#pragma unroll
        for (int it = 0; it < BITER; ++it) {
            const char* src = (const char*)W +
                ((size_t)(n0 + brow[it]) * ldw + k0) * 2 + bcol[it];
            __builtin_amdgcn_global_load_lds(
                (gptr_t)src,
                (lptr_t)((char*)Bs + (it * 256 + wid * 64) * 16), 16, 0, 0);
        }
        __syncthreads();

        bf16x8 av[FM], bv[FN];
#pragma unroll
        for (int fm = 0; fm < FM; ++fm) {
            int ra = wm * 64 + fm * 16 + fr;
            av[fm] = *(const bf16x8*)((const char*)As + ra * 64 + ((fq * 16) ^ swz));
        }
#pragma unroll
        for (int fn = 0; fn < FN; ++fn) {
            int rb = wn * WN + fn * 16 + fr;
            bv[fn] = *(const bf16x8*)((const char*)Bs + rb * 64 + ((fq * 16) ^ swz));
        }
#pragma unroll
        for (int fm = 0; fm < FM; ++fm)
#pragma unroll
            for (int fn = 0; fn < FN; ++fn)
                acc[fm][fn] = __builtin_amdgcn_mfma_f32_16x16x32_bf16(
                    av[fm], bv[fn], acc[fm][fn], 0, 0, 0);
        __syncthreads();
    }

#pragma unroll
    for (int fn = 0; fn < FN; ++fn) {
        long col = n0 + wn * WN + fn * 16 + fr;
        float bb = bias ? bias[col] : 0.0f;
#pragma unroll
        for (int fm = 0; fm < FM; ++fm) {
            long row0 = m0 + wm * 64 + fm * 16 + fq * 4;
#pragma unroll
            for (int r = 0; r < 4; ++r) {
                float v = acc[fm][fn][r] + bb;
                if (ACT == 1) v = fmaxf(v, 0.0f);
                else if (ACT == 2) v = fmaxf(v, 0.0f) + log1pf(__expf(-fabsf(v)));
                size_t o = (size_t)(row0 + r) * ldc + col;
                if (OUTBF) ((bf16*)Cp)[o] = f2bf(v);
                else       ((float*)Cp)[o] = v;
            }
        }
    }
}

// ---------------------------------------------------------------------------
struct CastJobs {
    const float* src[9];
    bf16* dst[9];
    int n[9];
};

__global__ __launch_bounds__(256)
void cast_bf16_kernel(CastJobs J)
{
    const int seg = blockIdx.y;
    const float* s = J.src[seg];
    bf16* d = J.dst[seg];
    const int n = J.n[seg];
    for (int i = blockIdx.x * 256 + threadIdx.x; i < n; i += gridDim.x * 256)
        d[i] = f2bf(s[i]);
}

#define DSTATE 16
#define CHUNK 64      // scan chunk (NC = L/64 = 32)
#define TT 16         // t-tile staged in LDS

// ---------------------------------------------------------------------------
// Depthwise causal conv (k=4) + bias + silu. bf16 in, bf16 out, f32 math.
// grid: (NB * L/32, 4), block 256.
// ---------------------------------------------------------------------------
__global__ __launch_bounds__(256)
void conv_silu_kernel(const bf16* __restrict__ xmr, const float* __restrict__ cw,
                      const float* __restrict__ cb, bf16* __restrict__ xms, int L)
{
    const int NCc = L / 32;
    const int c = blockIdx.x % NCc;
    const int b = blockIdx.x / NCc;
    const int d = blockIdx.y * 256 + threadIdx.x;

    const float w0 = cw[d * 4 + 0], w1 = cw[d * 4 + 1];
    const float w2 = cw[d * 4 + 2], w3 = cw[d * 4 + 3];
    const float bb = cb[d];

    const int t0 = c * 32;
    float x0 = 0.f, x1 = 0.f, x2 = 0.f;
    if (t0 >= 3) {
        x0 = bf2f(xmr[(size_t)(b * L + t0 - 3) * 1024 + d]);
        x1 = bf2f(xmr[(size_t)(b * L + t0 - 2) * 1024 + d]);
        x2 = bf2f(xmr[(size_t)(b * L + t0 - 1) * 1024 + d]);
    }
    for (int t = t0; t < t0 + 32; ++t) {
        float x3 = bf2f(xmr[(size_t)(b * L + t) * 1024 + d]);
        float v = fmaf(w0, x0, fmaf(w1, x1, fmaf(w2, x2, fmaf(w3, x3, bb))));
        xms[(size_t)(b * L + t) * 1024 + d] = f2bf(v * sigmoidf_(v));
        x0 = x1; x1 = x2; x2 = x3;
    }
}

// ---------------------------------------------------------------------------
// Scan pass 1 (LDS tile-staged): per chunk of 64 t's, P = prod(dA), S = local
// scan end. Streams delta/xms staged 16 t's at a time, coalesced bf16x8.
// grid: (NB*NC, 4), block 256 (one d per thread, 16 states in regs).
// ---------------------------------------------------------------------------
__global__ __launch_bounds__(256)
void scan_pass1(const bf16* __restrict__ delta, const bf16* __restrict__ xms,
                const bf16* __restrict__ dblb, const float* __restrict__ A_log,
                float* __restrict__ P, float* __restrict__ S, int L)
{
    const int NC = L / CHUNK;
    const int c = blockIdx.x % NC;
    const int b = blockIdx.x / NC;
    const int d0 = blockIdx.y * 256;
    const int tid = threadIdx.x;
    const int d = d0 + tid;

    __shared__ __align__(16) bf16 de_sh[TT][256];
    __shared__ __align__(16) bf16 x_sh[TT][256];
    __shared__ float Bsh[TT][DSTATE];

    float As_[DSTATE];
#pragma unroll
    for (int s = 0; s < DSTATE; ++s) As_[s] = -expf(A_log[(size_t)d * DSTATE + s]);

    float h[DSTATE], p[DSTATE];
#pragma unroll
    for (int s = 0; s < DSTATE; ++s) { h[s] = 0.f; p[s] = 1.f; }

    for (int tt = 0; tt < CHUNK / TT; ++tt) {
        const int t0 = c * CHUNK + tt * TT;
#pragma unroll
        for (int it = 0; it < 2; ++it) {
            int q = it * 256 + tid;
            int r = q >> 5, co = (q & 31) << 3;
            size_t g = (size_t)(b * L + t0 + r) * 1024 + d0 + co;
            *(bf16x8*)(&de_sh[r][co]) = *(const bf16x8*)(&delta[g]);
            *(bf16x8*)(&x_sh[r][co])  = *(const bf16x8*)(&xms[g]);
        }
        {
            int t = tid >> 4, s = tid & 15;
            Bsh[t][s] = bf2f(dblb[(size_t)(b * L + t0 + t) * 64 + 32 + s]);
        }
        __syncthreads();
#pragma unroll
        for (int t = 0; t < TT; ++t) {
            float de = bf2f(de_sh[t][tid]);
            float x  = bf2f(x_sh[t][tid]);
            float dx = de * x;
#pragma unroll
            for (int s = 0; s < DSTATE; ++s) {
                float dA = __expf(de * As_[s]);
                h[s] = fmaf(dA, h[s], dx * Bsh[t][s]);
                p[s] *= dA;
            }
        }
        __syncthreads();
    }
#pragma unroll
    for (int s = 0; s < DSTATE; ++s) {
        size_t o = ((size_t)(b * NC + c) * DSTATE + s) * 1024 + d;
        P[o] = p[s];
        S[o] = h[s];
    }
}

// ---------------------------------------------------------------------------
// Pass 2: serial combine over NC=32 chunks, Hinit in place of P.
// grid: NB*64 blocks of 256.
// ---------------------------------------------------------------------------
__global__ __launch_bounds__(256)
void scan_pass2(const float* P, const float* __restrict__ S, float* Hinit, int NC)
{
    int g = blockIdx.x * 256 + threadIdx.x;
    int d = g & 1023;
    int s = (g >> 10) & 15;
    int b = g >> 14;
    float h = 0.f;
    for (int c = 0; c < NC; ++c) {
        size_t o = ((size_t)(b * NC + c) * DSTATE + s) * 1024 + d;
        float p  = P[o];
        float sv = S[o];
        Hinit[o] = h;              // overwrites P[o] AFTER both loads
        h = fmaf(p, h, sv);
    }
}

// ---------------------------------------------------------------------------
// Pass 3 (LDS tile-staged): recompute local scan from Hinit,
// y = (sum_s h*C + xm*D) * silu(z), bf16 out. Y aliases delta (per-element
// staged-into-LDS-before-write; blocks own disjoint (c, d0) regions).
// ---------------------------------------------------------------------------
__global__ __launch_bounds__(256)
void scan_pass3(const bf16* delta, const bf16* __restrict__ xms,
                const bf16* __restrict__ dblb, const float* __restrict__ A_log,
                const float* __restrict__ Hinit, const float* __restrict__ Dp,
                const bf16* __restrict__ zb, bf16* Y, int L)
{
    const int NC = L / CHUNK;
    const int c = blockIdx.x % NC;
    const int b = blockIdx.x / NC;
    const int d0 = blockIdx.y * 256;
    const int tid = threadIdx.x;
    const int d = d0 + tid;

    __shared__ __align__(16) bf16 de_sh[TT][256];
    __shared__ __align__(16) bf16 x_sh[TT][256];
    __shared__ __align__(16) bf16 z_sh[TT][256];
    __shared__ float Bsh[TT][DSTATE];
    __shared__ float Csh[TT][DSTATE];

    float As_[DSTATE];
#pragma unroll
    for (int s = 0; s < DSTATE; ++s) As_[s] = -expf(A_log[(size_t)d * DSTATE + s]);

    float h[DSTATE];
#pragma unroll
    for (int s = 0; s < DSTATE; ++s)
        h[s] = Hinit[((size_t)(b * NC + c) * DSTATE + s) * 1024 + d];

    const float Dd = Dp[d];

    for (int tt = 0; tt < CHUNK / TT; ++tt) {
        const int t0 = c * CHUNK + tt * TT;
#pragma unroll
        for (int it = 0; it < 2; ++it) {
            int q = it * 256 + tid;
            int r = q >> 5, co = (q & 31) << 3;
            size_t g = (size_t)(b * L + t0 + r) * 1024 + d0 + co;
            *(bf16x8*)(&de_sh[r][co]) = *(const bf16x8*)(&delta[g]);
            *(bf16x8*)(&x_sh[r][co])  = *(const bf16x8*)(&xms[g]);
            *(bf16x8*)(&z_sh[r][co])  = *(const bf16x8*)(&zb[g]);
        }
        {
            int t = tid >> 4, s = tid & 15;
            size_t base = (size_t)(b * L + t0 + t) * 64;
            Bsh[t][s] = bf2f(dblb[base + 32 + s]);
            Csh[t][s] = bf2f(dblb[base + 48 + s]);
        }
        __syncthreads();
#pragma unroll
        for (int t = 0; t < TT; ++t) {
            float de = bf2f(de_sh[t][tid]);
            float x  = bf2f(x_sh[t][tid]);
            float dx = de * x;
            float y = 0.f;
#pragma unroll
            for (int s = 0; s < DSTATE; ++s) {
                float dA = __expf(de * As_[s]);
                h[s] = fmaf(dA, h[s], dx * Bsh[t][s]);
                y = fmaf(h[s], Csh[t][s], y);
            }
            y = fmaf(x, Dd, y);
            float z = bf2f(z_sh[t][tid]);
            Y[(size_t)(b * L + t0 + t) * 1024 + d] = f2bf(y * (z * sigmoidf_(z)));
        }
        __syncthreads();
    }
}

// ---------------------------------------------------------------------------

extern "C" void kernel_launch(void* const* d_in, const int* in_sizes, int n_in,
                              void* d_out, int out_size, void* d_ws, size_t ws_size,
                              hipStream_t stream)
{
    (void)in_sizes; (void)n_in; (void)out_size;

    const float* x         = (const float*)d_in[0];
    const float* enc_w1    = (const float*)d_in[1];
    const float* enc_b1    = (const float*)d_in[2];
    const float* enc_w2    = (const float*)d_in[3];
    const float* enc_b2    = (const float*)d_in[4];
    const float* in_proj_w = (const float*)d_in[5];
    const float* conv_w    = (const float*)d_in[6];
    const float* conv_b    = (const float*)d_in[7];
    const float* x_proj_w  = (const float*)d_in[8];
    const float* dt_proj_w = (const float*)d_in[9];
    const float* dt_proj_b = (const float*)d_in[10];
    const float* A_log     = (const float*)d_in[11];
    const float* D_param   = (const float*)d_in[12];
    const float* out_proj_w= (const float*)d_in[13];
    const float* dec_w1    = (const float*)d_in[14];
    const float* dec_b1    = (const float*)d_in[15];
    const float* dec_w2    = (const float*)d_in[16];
    const float* dec_b2    = (const float*)d_in[17];
    float* out = (float*)d_out;

    const int L = 2048, NC = L / CHUNK;   // NC = 32

    // ---- bf16 fixed region (weights + x) ----
    bf16* wb = (bf16*)d_ws;
    size_t off = 0;
    bf16* w_enc1 = wb + off; off += 16384;
    bf16* w_enc2 = wb + off; off += 131072;
    bf16* w_inpj = wb + off; off += 1048576;
    bf16* w_xprj = wb + off; off += 65536;
    bf16* w_dtpj = wb + off; off += 32768;
    bf16* w_outp = wb + off; off += 524288;
    bf16* w_dec1 = wb + off; off += 131072;
    bf16* w_dec2 = wb + off; off += 16384;
    bf16* xbf    = wb + off; off += 1048576;
    const size_t fixedB = off * 2;         // 6,029,312 B

    // per-row bytes:
    //   hbf(512) + ubf(1024) + slot3(2048) + zbf(2048) + xms(2048)
    //   + dblb(128) + Sf(1024) = 8832
    const size_t PER_ROW = 8832;
    int SPLIT = 8;
    if      (fixedB + (size_t)16384 * PER_ROW <= ws_size) SPLIT = 1;
    else if (fixedB + (size_t) 8192 * PER_ROW <= ws_size) SPLIT = 2;  // 78.4 MB
    else if (fixedB + (size_t) 4096 * PER_ROW <= ws_size) SPLIT = 4;

    const int NB = 8 / SPLIT;
    const int MR = NB * L;

    char* pb = (char*)d_ws + fixedB;
    bf16* hbf   = (bf16*)pb;                     // MR x 256
    bf16* ubf   = hbf   + (size_t)MR * 256;      // MR x 512 (u, o; P aliases)
    bf16* slot3 = ubf   + (size_t)MR * 512;      // MR x 1024 (xm_raw -> delta -> y)
    bf16* zbf   = slot3 + (size_t)MR * 1024;     // MR x 1024
    bf16* xms   = zbf   + (size_t)MR * 1024;     // MR x 1024
    bf16* dblb  = xms   + (size_t)MR * 1024;     // MR x 64
    float* Sf   = (float*)(dblb + (size_t)MR * 64);  // MR x 256 f32
    float* Pf   = (float*)ubf;                   // MR x 256 f32 == MR*1024 B

    // ---- casts (weights + x), every call ----
    CastJobs J;
    J.src[0] = enc_w1;     J.dst[0] = w_enc1; J.n[0] = 16384;
    J.src[1] = enc_w2;     J.dst[1] = w_enc2; J.n[1] = 131072;
    J.src[2] = in_proj_w;  J.dst[2] = w_inpj; J.n[2] = 1048576;
    J.src[3] = x_proj_w;   J.dst[3] = w_xprj; J.n[3] = 65536;
    J.src[4] = dt_proj_w;  J.dst[4] = w_dtpj; J.n[4] = 32768;
    J.src[5] = out_proj_w; J.dst[5] = w_outp; J.n[5] = 524288;
    J.src[6] = dec_w1;     J.dst[6] = w_dec1; J.n[6] = 131072;
    J.src[7] = dec_w2;     J.dst[7] = w_dec2; J.n[7] = 16384;
    J.src[8] = x;          J.dst[8] = xbf;    J.n[8] = 1048576;
    cast_bf16_kernel<<<dim3(128, 9), 256, 0, stream>>>(J);

    dim3 blk(256);
    for (int p = 0; p < SPLIT; ++p) {
        const bf16* xp  = xbf + (size_t)p * MR * 64;
        float*     outp = out + (size_t)p * MR * 64;

        // enc1: relu(x @ enc_w1^T + b1) -> h (MR x 256), K=64
        gemm_mfma<128,1,1><<<dim3(2, MR/128), blk, 0, stream>>>(
            xp, 64, w_enc1, 64, enc_b1, hbf, 256, 64);
        // enc2: u = h @ enc_w2^T + b2 (MR x 512), K=256
        gemm_mfma<128,0,1><<<dim3(4, MR/128), blk, 0, stream>>>(
            hbf, 256, w_enc2, 256, enc_b2, ubf, 512, 256);
        // in_proj xm half -> slot3 (bf16), K=512
        gemm_mfma<128,0,1><<<dim3(8, MR/128), blk, 0, stream>>>(
            ubf, 512, w_inpj, 512, nullptr, slot3, 1024, 512);
        // in_proj z half -> zbf
        gemm_mfma<128,0,1><<<dim3(8, MR/128), blk, 0, stream>>>(
            ubf, 512, w_inpj + (size_t)1024 * 512, 512, nullptr, zbf, 1024, 512);
        // conv + silu: slot3 -> xms
        conv_silu_kernel<<<dim3(NB * (L/32), 4), blk, 0, stream>>>(
            slot3, conv_w, conv_b, xms, L);
        // x_proj: dbl = xms @ x_proj_w^T (MR x 64), K=1024
        gemm_mfma<64,0,1><<<dim3(1, MR/128), blk, 0, stream>>>(
            xms, 1024, w_xprj, 1024, nullptr, dblb, 64, 1024);
        // dt_proj + softplus: delta (bf16) -> slot3 (xm_raw dead), K=32
        gemm_mfma<128,2,1><<<dim3(8, MR/128), blk, 0, stream>>>(
            dblb, 64, w_dtpj, 32, dt_proj_b, slot3, 1024, 32);
        // selective scan (CHUNK=64, NC=32)
        scan_pass1<<<dim3(NB * NC, 4), blk, 0, stream>>>(
            slot3, xms, dblb, A_log, Pf, Sf, L);
        scan_pass2<<<dim3(NB * 64), blk, 0, stream>>>(Pf, Sf, Pf, NC);
        scan_pass3<<<dim3(NB * NC, 4), blk, 0, stream>>>(
            slot3, xms, dblb, A_log, Pf, D_param, zbf, slot3 /*y*/, L);
        // out_proj: o = y @ out_proj_w^T (MR x 512), K=1024 (P dead)
        gemm_mfma<128,0,1><<<dim3(4, MR/128), blk, 0, stream>>>(
            slot3, 1024, w_outp, 1024, nullptr, ubf, 512, 1024);
        // dec1: relu(o @ dec_w1^T + b1) (MR x 256), K=512
        gemm_mfma<128,1,1><<<dim3(2, MR/128), blk, 0, stream>>>(
            ubf, 512, w_dec1, 512, dec_b1, hbf, 256, 512);
        // dec2: out = h2 @ dec_w2^T + b2 (MR x 64 f32), K=256
        gemm_mfma<64,0,0><<<dim3(1, MR/128), blk, 0, stream>>>(
            hbf, 256, w_dec2, 256, dec_b2, outp, 64, 256);
    }
}

// Round 7
// 440.954 us; speedup vs baseline: 1.4759x; 1.4759x over previous
//
#include <hip/hip_runtime.h>
#include <hip/hip_bf16.h>

typedef __attribute__((ext_vector_type(8))) short bf16x8;
typedef __attribute__((ext_vector_type(4))) float f32x4;
typedef __hip_bfloat16 bf16;

#define DEV __device__ __forceinline__
DEV float sigmoidf_(float x) { return 1.0f / (1.0f + __expf(-x)); }
DEV float bf2f(bf16 v) { return __bfloat162float(v); }
DEV bf16  f2bf(float v) { return __float2bfloat16(v); }

typedef const __attribute__((address_space(1))) void* gptr_t;
typedef __attribute__((address_space(3))) void* lptr_t;

// ---------------------------------------------------------------------------
// bf16 MFMA GEMM (verified R4/R6): C = act(A @ W^T + bias)
// BM=128, BK=32, 4 waves 2x2, 16x16x32 MFMA, global_load_lds w/ pre-swizzled
// source (byte ^= (row&3)<<4 inside the 64-B BK-row).
// ---------------------------------------------------------------------------
template<int BN, int ACT, int OUTBF>
__global__ __launch_bounds__(256)
void gemm_mfma(const bf16* __restrict__ A, int lda,
               const bf16* __restrict__ W, int ldw,
               const float* __restrict__ bias,
               void* __restrict__ Cp, int ldc, int K)
{
    constexpr int BM = 128, BK = 32;
    constexpr int WN = BN / 2;
    constexpr int FM = 4, FN = WN / 16;
    constexpr int AITER = (BM * BK * 2) / (256 * 16);
    constexpr int BITER = (BN * BK * 2) / (256 * 16);

    __shared__ __align__(16) ushort As[BM * BK];
    __shared__ __align__(16) ushort Bs[BN * BK];

    const int tid = threadIdx.x;
    const int lane = tid & 63;
    const int wid = tid >> 6;
    const int wm = wid >> 1, wn = wid & 1;
    const long m0 = (long)blockIdx.y * BM;
    const long n0 = (long)blockIdx.x * BN;

    f32x4 acc[FM][FN] = {};

    int arow[AITER], acol[AITER];
#pragma unroll
    for (int it = 0; it < AITER; ++it) {
        int q = it * 256 + tid;
        int r = q >> 2;
        arow[it] = r;
        acol[it] = ((q & 3) * 16) ^ ((r & 3) << 4);
    }
    int brow[BITER], bcol[BITER];
#pragma unroll
    for (int it = 0; it < BITER; ++it) {
        int q = it * 256 + tid;
        int r = q >> 2;
        brow[it] = r;
        bcol[it] = ((q & 3) * 16) ^ ((r & 3) << 4);
    }

    const int fr = lane & 15, fq = lane >> 4;
    const int swz = (fr & 3) << 4;

    for (int k0 = 0; k0 < K; k0 += BK) {
#pragma unroll
        for (int it = 0; it < AITER; ++it) {
            const char* src = (const char*)A +
                ((size_t)(m0 + arow[it]) * lda + k0) * 2 + acol[it];
            __builtin_amdgcn_global_load_lds(
                (gptr_t)src,
                (lptr_t)((char*)As + (it * 256 + wid * 64) * 16), 16, 0, 0);
        }
#pragma unroll
        for (int it = 0; it < BITER; ++it) {
            const char* src = (const char*)W +
                ((size_t)(n0 + brow[it]) * ldw + k0) * 2 + bcol[it];
            __builtin_amdgcn_global_load_lds(
                (gptr_t)src,
                (lptr_t)((char*)Bs + (it * 256 + wid * 64) * 16), 16, 0, 0);
        }
        __syncthreads();

        bf16x8 av[FM], bv[FN];
#pragma unroll
        for (int fm = 0; fm < FM; ++fm) {
            int ra = wm * 64 + fm * 16 + fr;
            av[fm] = *(const bf16x8*)((const char*)As + ra * 64 + ((fq * 16) ^ swz));
        }
#pragma unroll
        for (int fn = 0; fn < FN; ++fn) {
            int rb = wn * WN + fn * 16 + fr;
            bv[fn] = *(const bf16x8*)((const char*)Bs + rb * 64 + ((fq * 16) ^ swz));
        }
#pragma unroll
        for (int fm = 0; fm < FM; ++fm)
#pragma unroll
            for (int fn = 0; fn < FN; ++fn)
                acc[fm][fn] = __builtin_amdgcn_mfma_f32_16x16x32_bf16(
                    av[fm], bv[fn], acc[fm][fn], 0, 0, 0);
        __syncthreads();
    }

#pragma unroll
    for (int fn = 0; fn < FN; ++fn) {
        long col = n0 + wn * WN + fn * 16 + fr;
        float bb = bias ? bias[col] : 0.0f;
#pragma unroll
        for (int fm = 0; fm < FM; ++fm) {
            long row0 = m0 + wm * 64 + fm * 16 + fq * 4;
#pragma unroll
            for (int r = 0; r < 4; ++r) {
                float v = acc[fm][fn][r] + bb;
                if (ACT == 1) v = fmaxf(v, 0.0f);
                else if (ACT == 2) v = fmaxf(v, 0.0f) + log1pf(__expf(-fabsf(v)));
                size_t o = (size_t)(row0 + r) * ldc + col;
                if (OUTBF) ((bf16*)Cp)[o] = f2bf(v);
                else       ((float*)Cp)[o] = v;
            }
        }
    }
}

// ---------------------------------------------------------------------------
struct CastJobs {
    const float* src[9];
    bf16* dst[9];
    int n[9];
};

__global__ __launch_bounds__(256)
void cast_bf16_kernel(CastJobs J)
{
    const int seg = blockIdx.y;
    const float* s = J.src[seg];
    bf16* d = J.dst[seg];
    const int n = J.n[seg];
    for (int i = blockIdx.x * 256 + threadIdx.x; i < n; i += gridDim.x * 256)
        d[i] = f2bf(s[i]);
}

#define DSTATE 16
#define CHUNK 32      // scan chunk (NC = L/32 = 64)

// ---------------------------------------------------------------------------
// Depthwise causal conv (k=4) + bias + silu. bf16 in/out, f32 math.
// ---------------------------------------------------------------------------
__global__ __launch_bounds__(256)
void conv_silu_kernel(const bf16* __restrict__ xmr, const float* __restrict__ cw,
                      const float* __restrict__ cb, bf16* __restrict__ xms, int L)
{
    const int NCc = L / 32;
    const int c = blockIdx.x % NCc;
    const int b = blockIdx.x / NCc;
    const int d = blockIdx.y * 256 + threadIdx.x;

    const float w0 = cw[d * 4 + 0], w1 = cw[d * 4 + 1];
    const float w2 = cw[d * 4 + 2], w3 = cw[d * 4 + 3];
    const float bb = cb[d];

    const int t0 = c * 32;
    float x0 = 0.f, x1 = 0.f, x2 = 0.f;
    if (t0 >= 3) {
        x0 = bf2f(xmr[(size_t)(b * L + t0 - 3) * 1024 + d]);
        x1 = bf2f(xmr[(size_t)(b * L + t0 - 2) * 1024 + d]);
        x2 = bf2f(xmr[(size_t)(b * L + t0 - 1) * 1024 + d]);
    }
    for (int t = t0; t < t0 + 32; ++t) {
        float x3 = bf2f(xmr[(size_t)(b * L + t) * 1024 + d]);
        float v = fmaf(w0, x0, fmaf(w1, x1, fmaf(w2, x2, fmaf(w3, x3, bb))));
        xms[(size_t)(b * L + t) * 1024 + d] = f2bf(v * sigmoidf_(v));
        x0 = x1; x1 = x2; x2 = x3;
    }
}

// ---------------------------------------------------------------------------
// A-matrix helpers: detect A_s == -(s+1) (true for this model: A_log =
// log(arange(1..16)) broadcast). Wave-uniform flag; exact fallback kept.
// ---------------------------------------------------------------------------
DEV bool load_A(const float* __restrict__ A_log, int d, float* As_)
{
    bool fastA = true;
#pragma unroll
    for (int s = 0; s < DSTATE; ++s) {
        As_[s] = -__expf(A_log[(size_t)d * DSTATE + s]);
        fastA = fastA && (fabsf(As_[s] + (float)(s + 1)) <= 1e-4f * (s + 1));
    }
    return fastA;
}

// ---------------------------------------------------------------------------
// Scan pass 1 (direct loads, R4 structure): per chunk of 32 t's,
// P = prod(dA), S = local scan end. grid: (NB*NC, 4), block 256.
// ---------------------------------------------------------------------------
__global__ __launch_bounds__(256)
void scan_pass1(const bf16* __restrict__ delta, const bf16* __restrict__ xms,
                const bf16* __restrict__ dblb, const float* __restrict__ A_log,
                float* __restrict__ P, float* __restrict__ S, int L)
{
    const int NC = L / CHUNK;
    const int c = blockIdx.x % NC;
    const int b = blockIdx.x / NC;
    const int d = blockIdx.y * 256 + threadIdx.x;

    __shared__ float Bsh[CHUNK][DSTATE];
#pragma unroll
    for (int it = 0; it < CHUNK * DSTATE / 256; ++it) {
        int idx = threadIdx.x + it * 256;
        int t = idx >> 4, s = idx & 15;
        Bsh[t][s] = bf2f(dblb[(size_t)(b * L + c * CHUNK + t) * 64 + 32 + s]);
    }
    __syncthreads();

    float As_[DSTATE];
    const bool fastA = load_A(A_log, d, As_);

    float h[DSTATE], p[DSTATE];
#pragma unroll
    for (int s = 0; s < DSTATE; ++s) { h[s] = 0.f; p[s] = 1.f; }

    if (fastA) {
        for (int t = 0; t < CHUNK; ++t) {
            size_t row = (size_t)(b * L + c * CHUNK + t);
            float de = bf2f(delta[row * 1024 + d]);
            float x  = bf2f(xms[row * 1024 + d]);
            float dx = de * x;
            float r = __expf(-de);
            float a = r;
#pragma unroll
            for (int s = 0; s < DSTATE; ++s) {
                h[s] = fmaf(a, h[s], dx * Bsh[t][s]);
                p[s] *= a;
                a *= r;
            }
        }
    } else {
        for (int t = 0; t < CHUNK; ++t) {
            size_t row = (size_t)(b * L + c * CHUNK + t);
            float de = bf2f(delta[row * 1024 + d]);
            float x  = bf2f(xms[row * 1024 + d]);
            float dx = de * x;
#pragma unroll
            for (int s = 0; s < DSTATE; ++s) {
                float dA = __expf(de * As_[s]);
                h[s] = fmaf(dA, h[s], dx * Bsh[t][s]);
                p[s] *= dA;
            }
        }
    }
#pragma unroll
    for (int s = 0; s < DSTATE; ++s) {
        size_t o = ((size_t)(b * NC + c) * DSTATE + s) * 1024 + d;
        P[o] = p[s];
        S[o] = h[s];
    }
}

// ---------------------------------------------------------------------------
// Pass 2: serial combine over NC=64 chunks, Hinit in place of P.
// grid: NB*64 blocks of 256.
// ---------------------------------------------------------------------------
__global__ __launch_bounds__(256)
void scan_pass2(const float* P, const float* __restrict__ S, float* Hinit, int NC)
{
    int g = blockIdx.x * 256 + threadIdx.x;
    int d = g & 1023;
    int s = (g >> 10) & 15;
    int b = g >> 14;
    float h = 0.f;
    for (int c = 0; c < NC; ++c) {
        size_t o = ((size_t)(b * NC + c) * DSTATE + s) * 1024 + d;
        float p  = P[o];
        float sv = S[o];
        Hinit[o] = h;              // overwrites P[o] AFTER both loads
        h = fmaf(p, h, sv);
    }
}

// ---------------------------------------------------------------------------
// Pass 3 (direct loads, R4 structure): recompute local scan from Hinit,
// y = (sum_s h*C + xm*D) * silu(z), bf16 out. Y aliases delta (same-element
// read-then-write by the same thread).
// ---------------------------------------------------------------------------
__global__ __launch_bounds__(256)
void scan_pass3(const bf16* delta, const bf16* __restrict__ xms,
                const bf16* __restrict__ dblb, const float* __restrict__ A_log,
                const float* __restrict__ Hinit, const float* __restrict__ Dp,
                const bf16* __restrict__ zb, bf16* Y, int L)
{
    const int NC = L / CHUNK;
    const int c = blockIdx.x % NC;
    const int b = blockIdx.x / NC;
    const int d = blockIdx.y * 256 + threadIdx.x;

    __shared__ float Bsh[CHUNK][DSTATE];
    __shared__ float Csh[CHUNK][DSTATE];
#pragma unroll
    for (int it = 0; it < CHUNK * DSTATE / 256; ++it) {
        int idx = threadIdx.x + it * 256;
        int t = idx >> 4, s = idx & 15;
        size_t base = (size_t)(b * L + c * CHUNK + t) * 64;
        Bsh[t][s] = bf2f(dblb[base + 32 + s]);
        Csh[t][s] = bf2f(dblb[base + 48 + s]);
    }
    __syncthreads();

    float As_[DSTATE];
    const bool fastA = load_A(A_log, d, As_);

    float h[DSTATE];
#pragma unroll
    for (int s = 0; s < DSTATE; ++s)
        h[s] = Hinit[((size_t)(b * NC + c) * DSTATE + s) * 1024 + d];

    const float Dd = Dp[d];

    if (fastA) {
        for (int t = 0; t < CHUNK; ++t) {
            size_t row = (size_t)(b * L + c * CHUNK + t);
            float de = bf2f(delta[row * 1024 + d]);
            float x  = bf2f(xms[row * 1024 + d]);
            float dx = de * x;
            float r = __expf(-de);
            float a = r;
            float y0 = 0.f, y1 = 0.f;
#pragma unroll
            for (int s = 0; s < DSTATE; s += 2) {
                h[s] = fmaf(a, h[s], dx * Bsh[t][s]);
                y0 = fmaf(h[s], Csh[t][s], y0);
                a *= r;
                h[s+1] = fmaf(a, h[s+1], dx * Bsh[t][s+1]);
                y1 = fmaf(h[s+1], Csh[t][s+1], y1);
                a *= r;
            }
            float y = y0 + y1 + x * Dd;
            float z = bf2f(zb[row * 1024 + d]);
            Y[row * 1024 + d] = f2bf(y * (z * sigmoidf_(z)));
        }
    } else {
        for (int t = 0; t < CHUNK; ++t) {
            size_t row = (size_t)(b * L + c * CHUNK + t);
            float de = bf2f(delta[row * 1024 + d]);
            float x  = bf2f(xms[row * 1024 + d]);
            float dx = de * x;
            float y0 = 0.f, y1 = 0.f;
#pragma unroll
            for (int s = 0; s < DSTATE; s += 2) {
                float dA0 = __expf(de * As_[s]);
                float dA1 = __expf(de * As_[s+1]);
                h[s] = fmaf(dA0, h[s], dx * Bsh[t][s]);
                y0 = fmaf(h[s], Csh[t][s], y0);
                h[s+1] = fmaf(dA1, h[s+1], dx * Bsh[t][s+1]);
                y1 = fmaf(h[s+1], Csh[t][s+1], y1);
            }
            float y = y0 + y1 + x * Dd;
            float z = bf2f(zb[row * 1024 + d]);
            Y[row * 1024 + d] = f2bf(y * (z * sigmoidf_(z)));
        }
    }
}

// ---------------------------------------------------------------------------

extern "C" void kernel_launch(void* const* d_in, const int* in_sizes, int n_in,
                              void* d_out, int out_size, void* d_ws, size_t ws_size,
                              hipStream_t stream)
{
    (void)in_sizes; (void)n_in; (void)out_size;

    const float* x         = (const float*)d_in[0];
    const float* enc_w1    = (const float*)d_in[1];
    const float* enc_b1    = (const float*)d_in[2];
    const float* enc_w2    = (const float*)d_in[3];
    const float* enc_b2    = (const float*)d_in[4];
    const float* in_proj_w = (const float*)d_in[5];
    const float* conv_w    = (const float*)d_in[6];
    const float* conv_b    = (const float*)d_in[7];
    const float* x_proj_w  = (const float*)d_in[8];
    const float* dt_proj_w = (const float*)d_in[9];
    const float* dt_proj_b = (const float*)d_in[10];
    const float* A_log     = (const float*)d_in[11];
    const float* D_param   = (const float*)d_in[12];
    const float* out_proj_w= (const float*)d_in[13];
    const float* dec_w1    = (const float*)d_in[14];
    const float* dec_b1    = (const float*)d_in[15];
    const float* dec_w2    = (const float*)d_in[16];
    const float* dec_b2    = (const float*)d_in[17];
    float* out = (float*)d_out;

    const int L = 2048, NC = L / CHUNK;   // NC = 64

    // ---- bf16 fixed region (weights + x) ----
    bf16* wb = (bf16*)d_ws;
    size_t off = 0;
    bf16* w_enc1 = wb + off; off += 16384;
    bf16* w_enc2 = wb + off; off += 131072;
    bf16* w_inpj = wb + off; off += 1048576;
    bf16* w_xprj = wb + off; off += 65536;
    bf16* w_dtpj = wb + off; off += 32768;
    bf16* w_outp = wb + off; off += 524288;
    bf16* w_dec1 = wb + off; off += 131072;
    bf16* w_dec2 = wb + off; off += 16384;
    bf16* xbf    = wb + off; off += 1048576;
    const size_t fixedB = off * 2;         // 6,029,312 B

    // per-row bytes:
    //   hbf(512) + ubf(1024) + slot3(2048) + zbf(2048) + xms(2048)
    //   + dblb(128) + Pf(2048 f32) + Sf(2048 f32) = 11904
    const size_t PER_ROW = 11904;
    int SPLIT = 8;
    if      (fixedB + (size_t)16384 * PER_ROW <= ws_size) SPLIT = 1;
    else if (fixedB + (size_t) 8192 * PER_ROW <= ws_size) SPLIT = 2;  // 103.5 MB
    else if (fixedB + (size_t) 4096 * PER_ROW <= ws_size) SPLIT = 4;  //  54.8 MB

    const int NB = 8 / SPLIT;
    const int MR = NB * L;

    char* pb = (char*)d_ws + fixedB;
    bf16* hbf   = (bf16*)pb;                     // MR x 256
    bf16* ubf   = hbf   + (size_t)MR * 256;      // MR x 512 (u, o)
    bf16* slot3 = ubf   + (size_t)MR * 512;      // MR x 1024 (xm_raw -> delta -> y)
    bf16* zbf   = slot3 + (size_t)MR * 1024;     // MR x 1024
    bf16* xms   = zbf   + (size_t)MR * 1024;     // MR x 1024
    bf16* dblb  = xms   + (size_t)MR * 1024;     // MR x 64
    float* Pf   = (float*)(dblb + (size_t)MR * 64);  // MR x 512 f32 (-> Hinit)
    float* Sf   = Pf + (size_t)MR * 512;             // MR x 512 f32

    // ---- casts (weights + x), every call ----
    CastJobs J;
    J.src[0] = enc_w1;     J.dst[0] = w_enc1; J.n[0] = 16384;
    J.src[1] = enc_w2;     J.dst[1] = w_enc2; J.n[1] = 131072;
    J.src[2] = in_proj_w;  J.dst[2] = w_inpj; J.n[2] = 1048576;
    J.src[3] = x_proj_w;   J.dst[3] = w_xprj; J.n[3] = 65536;
    J.src[4] = dt_proj_w;  J.dst[4] = w_dtpj; J.n[4] = 32768;
    J.src[5] = out_proj_w; J.dst[5] = w_outp; J.n[5] = 524288;
    J.src[6] = dec_w1;     J.dst[6] = w_dec1; J.n[6] = 131072;
    J.src[7] = dec_w2;     J.dst[7] = w_dec2; J.n[7] = 16384;
    J.src[8] = x;          J.dst[8] = xbf;    J.n[8] = 1048576;
    cast_bf16_kernel<<<dim3(128, 9), 256, 0, stream>>>(J);

    dim3 blk(256);
    for (int p = 0; p < SPLIT; ++p) {
        const bf16* xp  = xbf + (size_t)p * MR * 64;
        float*     outp = out + (size_t)p * MR * 64;

        // enc1: relu(x @ enc_w1^T + b1) -> h (MR x 256), K=64
        gemm_mfma<128,1,1><<<dim3(2, MR/128), blk, 0, stream>>>(
            xp, 64, w_enc1, 64, enc_b1, hbf, 256, 64);
        // enc2: u = h @ enc_w2^T + b2 (MR x 512), K=256
        gemm_mfma<128,0,1><<<dim3(4, MR/128), blk, 0, stream>>>(
            hbf, 256, w_enc2, 256, enc_b2, ubf, 512, 256);
        // in_proj xm half -> slot3 (bf16), K=512
        gemm_mfma<128,0,1><<<dim3(8, MR/128), blk, 0, stream>>>(
            ubf, 512, w_inpj, 512, nullptr, slot3, 1024, 512);
        // in_proj z half -> zbf
        gemm_mfma<128,0,1><<<dim3(8, MR/128), blk, 0, stream>>>(
            ubf, 512, w_inpj + (size_t)1024 * 512, 512, nullptr, zbf, 1024, 512);
        // conv + silu: slot3 -> xms
        conv_silu_kernel<<<dim3(NB * (L/32), 4), blk, 0, stream>>>(
            slot3, conv_w, conv_b, xms, L);
        // x_proj: dbl = xms @ x_proj_w^T (MR x 64), K=1024
        gemm_mfma<64,0,1><<<dim3(1, MR/128), blk, 0, stream>>>(
            xms, 1024, w_xprj, 1024, nullptr, dblb, 64, 1024);
        // dt_proj + softplus: delta (bf16) -> slot3 (xm_raw dead), K=32
        gemm_mfma<128,2,1><<<dim3(8, MR/128), blk, 0, stream>>>(
            dblb, 64, w_dtpj, 32, dt_proj_b, slot3, 1024, 32);
        // selective scan (CHUNK=32, NC=64)
        scan_pass1<<<dim3(NB * NC, 4), blk, 0, stream>>>(
            slot3, xms, dblb, A_log, Pf, Sf, L);
        scan_pass2<<<dim3(NB * 64), blk, 0, stream>>>(Pf, Sf, Pf, NC);
        scan_pass3<<<dim3(NB * NC, 4), blk, 0, stream>>>(
            slot3, xms, dblb, A_log, Pf, D_param, zbf, slot3 /*y*/, L);
        // out_proj: o = y @ out_proj_w^T (MR x 512), K=1024
        gemm_mfma<128,0,1><<<dim3(4, MR/128), blk, 0, stream>>>(
            slot3, 1024, w_outp, 1024, nullptr, ubf, 512, 1024);
        // dec1: relu(o @ dec_w1^T + b1) (MR x 256), K=512
        gemm_mfma<128,1,1><<<dim3(2, MR/128), blk, 0, stream>>>(
            ubf, 512, w_dec1, 512, dec_b1, hbf, 256, 512);
        // dec2: out = h2 @ dec_w2^T + b2 (MR x 64 f32), K=256
        gemm_mfma<64,0,0><<<dim3(1, MR/128), blk, 0, stream>>>(
            hbf, 256, w_dec2, 256, dec_b2, outp, 64, 256);
    }
}

// Round 8
// 370.251 us; speedup vs baseline: 1.7578x; 1.1910x over previous
//
#include <hip/hip_runtime.h>
#include <hip/hip_bf16.h>

typedef __attribute__((ext_vector_type(8))) short bf16x8;
typedef __attribute__((ext_vector_type(4))) float f32x4;
typedef __attribute__((ext_vector_type(4))) unsigned short u16x4;
typedef __hip_bfloat16 bf16;

#define DEV __device__ __forceinline__
DEV float sigmoidf_(float x) { return 1.0f / (1.0f + __expf(-x)); }
DEV float bf2f(bf16 v) { return __bfloat162float(v); }
DEV bf16  f2bf(float v) { return __float2bfloat16(v); }

typedef const __attribute__((address_space(1))) void* gptr_t;
typedef __attribute__((address_space(3))) void* lptr_t;

template<int N> DEV void waitcnt_vm() {
    if constexpr (N == 0) asm volatile("s_waitcnt vmcnt(0)" ::: "memory");
    else if constexpr (N == 2) asm volatile("s_waitcnt vmcnt(2)" ::: "memory");
    else if constexpr (N == 3) asm volatile("s_waitcnt vmcnt(3)" ::: "memory");
    else asm volatile("s_waitcnt vmcnt(4)" ::: "memory");
}

// ---------------------------------------------------------------------------
// bf16 MFMA GEMM v2: C = act(A @ W^T + bias)
// - 2-phase double-buffered global_load_lds pipeline, counted vmcnt (never 0
//   mid-loop), raw s_barrier + lgkmcnt(0)+sched_barrier tail (rule #18).
// - source pre-swizzle byte ^= (row&3)<<4 within 64-B BK-row (R4-verified).
// - coalesced epilogue: acc -> bf16 LDS tile (64-row chunks, padded stride)
//   -> bf16x8 16B/lane stores (fixes 3.5x write amplification seen in R7).
// ACT: 0 none, 1 relu, 2 softplus. OUTBF: 1 bf16 out, 0 f32 (scalar path).
// ---------------------------------------------------------------------------
template<int BM, int BN, int ACT, int OUTBF>
__global__ __launch_bounds__(256)
void gemm_mfma(const bf16* __restrict__ A, int lda,
               const bf16* __restrict__ W, int ldw,
               const float* __restrict__ bias,
               void* __restrict__ Cp, int ldc, int K)
{
    constexpr int BK = 32;
    constexpr int WMS = BM / 2, WNS = BN / 2;
    constexpr int FM = WMS / 16, FN = WNS / 16;
    constexpr int AITER = (BM * BK) / (256 * 8);
    constexpr int BITER = (BN * BK) / (256 * 8);
    constexpr int NLD = AITER + BITER;
    constexpr int BUFB = (BM + BN) * BK * 2;    // bytes per buffer

    __shared__ __align__(16) char smem[2 * BUFB];

    const int tid = threadIdx.x;
    const int lane = tid & 63;
    const int wid = tid >> 6;
    const int wm = wid >> 1, wn = wid & 1;
    const long m0 = (long)blockIdx.y * BM;
    const long n0 = (long)blockIdx.x * BN;

    f32x4 acc[FM][FN] = {};

    long aoff[AITER];
#pragma unroll
    for (int it = 0; it < AITER; ++it) {
        int q = it * 256 + tid;
        int r = q >> 2;
        aoff[it] = (long)(m0 + r) * lda * 2 + (((q & 3) * 16) ^ ((r & 3) << 4));
    }
    long boff[BITER];
#pragma unroll
    for (int it = 0; it < BITER; ++it) {
        int q = it * 256 + tid;
        int r = q >> 2;
        boff[it] = (long)(n0 + r) * ldw * 2 + (((q & 3) * 16) ^ ((r & 3) << 4));
    }

    const char* Ac = (const char*)A;
    const char* Wc = (const char*)W;

    // prologue: stage tile 0 into buffer 0
#pragma unroll
    for (int it = 0; it < AITER; ++it)
        __builtin_amdgcn_global_load_lds((gptr_t)(Ac + aoff[it]),
            (lptr_t)(smem + (it * 256 + wid * 64) * 16), 16, 0, 0);
#pragma unroll
    for (int it = 0; it < BITER; ++it)
        __builtin_amdgcn_global_load_lds((gptr_t)(Wc + boff[it]),
            (lptr_t)(smem + BM * BK * 2 + (it * 256 + wid * 64) * 16), 16, 0, 0);

    const int NK = K / BK;
    const int fr = lane & 15, fq = lane >> 4;
    const int swz = (fr & 3) << 4;
    int cur = 0;

    for (int ks = 0; ks < NK; ++ks) {
        if (ks + 1 < NK) {
            const long k2 = (long)(ks + 1) * BK * 2;
            char* dst = smem + (cur ^ 1) * BUFB;
#pragma unroll
            for (int it = 0; it < AITER; ++it)
                __builtin_amdgcn_global_load_lds((gptr_t)(Ac + aoff[it] + k2),
                    (lptr_t)(dst + (it * 256 + wid * 64) * 16), 16, 0, 0);
#pragma unroll
            for (int it = 0; it < BITER; ++it)
                __builtin_amdgcn_global_load_lds((gptr_t)(Wc + boff[it] + k2),
                    (lptr_t)(dst + BM * BK * 2 + (it * 256 + wid * 64) * 16), 16, 0, 0);
            waitcnt_vm<NLD>();           // current tile's loads complete
        } else {
            waitcnt_vm<0>();
        }
        __builtin_amdgcn_s_barrier();    // all waves: current tile resident
        __builtin_amdgcn_sched_barrier(0);

        const char* base = smem + cur * BUFB;
        bf16x8 av[FM], bv[FN];
#pragma unroll
        for (int fm = 0; fm < FM; ++fm) {
            int ra = wm * WMS + fm * 16 + fr;
            av[fm] = *(const bf16x8*)(base + ra * 64 + ((fq * 16) ^ swz));
        }
#pragma unroll
        for (int fn = 0; fn < FN; ++fn) {
            int rb = wn * WNS + fn * 16 + fr;
            bv[fn] = *(const bf16x8*)(base + BM * BK * 2 + rb * 64 + ((fq * 16) ^ swz));
        }
#pragma unroll
        for (int fm = 0; fm < FM; ++fm)
#pragma unroll
            for (int fn = 0; fn < FN; ++fn)
                acc[fm][fn] = __builtin_amdgcn_mfma_f32_16x16x32_bf16(
                    av[fm], bv[fn], acc[fm][fn], 0, 0, 0);

        asm volatile("s_waitcnt lgkmcnt(0)" ::: "memory");
        __builtin_amdgcn_sched_barrier(0);
        __builtin_amdgcn_s_barrier();    // reads done; next stage may overwrite
        cur ^= 1;
    }

    // bias per output column (per fn)
    float bcol[FN];
#pragma unroll
    for (int fn = 0; fn < FN; ++fn)
        bcol[fn] = bias ? bias[n0 + wn * WNS + fn * 16 + fr] : 0.0f;

    if constexpr (OUTBF) {
        // coalesced epilogue via LDS, 64-row chunks
        constexpr int CST = BN + 8;              // padded row stride (elems)
        bf16* ct = (bf16*)smem;
        for (int mh = 0; mh < BM / 64; ++mh) {
            __syncthreads();
            if (BM == 64 || wm == mh) {
#pragma unroll
                for (int fm = 0; fm < FM; ++fm) {
                    int lr0 = (BM == 64 ? wm * WMS : 0) + fm * 16 + fq * 4;
#pragma unroll
                    for (int fn = 0; fn < FN; ++fn) {
                        int lc = wn * WNS + fn * 16 + fr;
#pragma unroll
                        for (int r = 0; r < 4; ++r) {
                            float v = acc[fm][fn][r] + bcol[fn];
                            if (ACT == 1) v = fmaxf(v, 0.0f);
                            else if (ACT == 2)
                                v = fmaxf(v, 0.0f) + __logf(1.0f + __expf(-fabsf(v)));
                            ct[(lr0 + r) * CST + lc] = f2bf(v);
                        }
                    }
                }
            }
            __syncthreads();
            constexpr int GPR = BN / 8;          // bf16x8 groups per row
#pragma unroll
            for (int it = 0; it < (64 * GPR) / 256; ++it) {
                int idx = it * 256 + tid;
                int row = idx / GPR, cg = idx % GPR;
                bf16x8 v8 = *(const bf16x8*)&ct[row * CST + cg * 8];
                *(bf16x8*)((bf16*)Cp + (size_t)(m0 + mh * 64 + row) * ldc
                           + n0 + cg * 8) = v8;
            }
        }
    } else {
        // f32 scalar epilogue (dec2 only: small output)
#pragma unroll
        for (int fn = 0; fn < FN; ++fn) {
            long col = n0 + wn * WNS + fn * 16 + fr;
#pragma unroll
            for (int fm = 0; fm < FM; ++fm) {
                long row0 = m0 + wm * WMS + fm * 16 + fq * 4;
#pragma unroll
                for (int r = 0; r < 4; ++r) {
                    float v = acc[fm][fn][r] + bcol[fn];
                    if (ACT == 1) v = fmaxf(v, 0.0f);
                    ((float*)Cp)[(size_t)(row0 + r) * ldc + col] = v;
                }
            }
        }
    }
}

// ---------------------------------------------------------------------------
struct CastJobs {
    const float* src[9];
    bf16* dst[9];
    int n[9];
};

__global__ __launch_bounds__(256)
void cast_bf16_kernel(CastJobs J)
{
    const int seg = blockIdx.y;
    const f32x4* s = (const f32x4*)J.src[seg];
    u16x4* d = (u16x4*)J.dst[seg];
    const int n4 = J.n[seg] >> 2;     // all sizes divisible by 4
    for (int i = blockIdx.x * 256 + threadIdx.x; i < n4; i += gridDim.x * 256) {
        f32x4 v = s[i];
        u16x4 o;
#pragma unroll
        for (int j = 0; j < 4; ++j) {
            bf16 b = f2bf(v[j]);
            o[j] = *(unsigned short*)&b;
        }
        d[i] = o;
    }
}

#define DSTATE 16
#define CHUNK 32      // scan chunk (NC = L/32 = 64)

// ---------------------------------------------------------------------------
// Depthwise causal conv (k=4) + bias + silu. bf16 in/out, f32 math.
// ---------------------------------------------------------------------------
__global__ __launch_bounds__(256)
void conv_silu_kernel(const bf16* __restrict__ xmr, const float* __restrict__ cw,
                      const float* __restrict__ cb, bf16* __restrict__ xms, int L)
{
    const int NCc = L / 32;
    const int c = blockIdx.x % NCc;
    const int b = blockIdx.x / NCc;
    const int d = blockIdx.y * 256 + threadIdx.x;

    const float w0 = cw[d * 4 + 0], w1 = cw[d * 4 + 1];
    const float w2 = cw[d * 4 + 2], w3 = cw[d * 4 + 3];
    const float bb = cb[d];

    const int t0 = c * 32;
    float x0 = 0.f, x1 = 0.f, x2 = 0.f;
    if (t0 >= 3) {
        x0 = bf2f(xmr[(size_t)(b * L + t0 - 3) * 1024 + d]);
        x1 = bf2f(xmr[(size_t)(b * L + t0 - 2) * 1024 + d]);
        x2 = bf2f(xmr[(size_t)(b * L + t0 - 1) * 1024 + d]);
    }
    for (int t = t0; t < t0 + 32; ++t) {
        float x3 = bf2f(xmr[(size_t)(b * L + t) * 1024 + d]);
        float v = fmaf(w0, x0, fmaf(w1, x1, fmaf(w2, x2, fmaf(w3, x3, bb))));
        xms[(size_t)(b * L + t) * 1024 + d] = f2bf(v * sigmoidf_(v));
        x0 = x1; x1 = x2; x2 = x3;
    }
}

// ---------------------------------------------------------------------------
// A-matrix helper: detect A_s == -(s+1) (A_log = log(arange(1..16)) broadcast).
// ---------------------------------------------------------------------------
DEV bool load_A(const float* __restrict__ A_log, int d, float* As_)
{
    bool fastA = true;
#pragma unroll
    for (int s = 0; s < DSTATE; ++s) {
        As_[s] = -__expf(A_log[(size_t)d * DSTATE + s]);
        fastA = fastA && (fabsf(As_[s] + (float)(s + 1)) <= 1e-4f * (s + 1));
    }
    return fastA;
}

// ---------------------------------------------------------------------------
// Scan pass 1 (direct loads, R7-verified)
// ---------------------------------------------------------------------------
__global__ __launch_bounds__(256)
void scan_pass1(const bf16* __restrict__ delta, const bf16* __restrict__ xms,
                const bf16* __restrict__ dblb, const float* __restrict__ A_log,
                float* __restrict__ P, float* __restrict__ S, int L)
{
    const int NC = L / CHUNK;
    const int c = blockIdx.x % NC;
    const int b = blockIdx.x / NC;
    const int d = blockIdx.y * 256 + threadIdx.x;

    __shared__ float Bsh[CHUNK][DSTATE];
#pragma unroll
    for (int it = 0; it < CHUNK * DSTATE / 256; ++it) {
        int idx = threadIdx.x + it * 256;
        int t = idx >> 4, s = idx & 15;
        Bsh[t][s] = bf2f(dblb[(size_t)(b * L + c * CHUNK + t) * 64 + 32 + s]);
    }
    __syncthreads();

    float As_[DSTATE];
    const bool fastA = load_A(A_log, d, As_);

    float h[DSTATE], p[DSTATE];
#pragma unroll
    for (int s = 0; s < DSTATE; ++s) { h[s] = 0.f; p[s] = 1.f; }

    if (fastA) {
        for (int t = 0; t < CHUNK; ++t) {
            size_t row = (size_t)(b * L + c * CHUNK + t);
            float de = bf2f(delta[row * 1024 + d]);
            float x  = bf2f(xms[row * 1024 + d]);
            float dx = de * x;
            float r = __expf(-de);
            float a = r;
#pragma unroll
            for (int s = 0; s < DSTATE; ++s) {
                h[s] = fmaf(a, h[s], dx * Bsh[t][s]);
                p[s] *= a;
                a *= r;
            }
        }
    } else {
        for (int t = 0; t < CHUNK; ++t) {
            size_t row = (size_t)(b * L + c * CHUNK + t);
            float de = bf2f(delta[row * 1024 + d]);
            float x  = bf2f(xms[row * 1024 + d]);
            float dx = de * x;
#pragma unroll
            for (int s = 0; s < DSTATE; ++s) {
                float dA = __expf(de * As_[s]);
                h[s] = fmaf(dA, h[s], dx * Bsh[t][s]);
                p[s] *= dA;
            }
        }
    }
#pragma unroll
    for (int s = 0; s < DSTATE; ++s) {
        size_t o = ((size_t)(b * NC + c) * DSTATE + s) * 1024 + d;
        P[o] = p[s];
        S[o] = h[s];
    }
}

// ---------------------------------------------------------------------------
// Pass 2: serial combine over chunks, Hinit in place of P.
// ---------------------------------------------------------------------------
__global__ __launch_bounds__(256)
void scan_pass2(const float* P, const float* __restrict__ S, float* Hinit, int NC)
{
    int g = blockIdx.x * 256 + threadIdx.x;
    int d = g & 1023;
    int s = (g >> 10) & 15;
    int b = g >> 14;
    float h = 0.f;
    for (int c = 0; c < NC; ++c) {
        size_t o = ((size_t)(b * NC + c) * DSTATE + s) * 1024 + d;
        float p  = P[o];
        float sv = S[o];
        Hinit[o] = h;              // overwrites P[o] AFTER both loads
        h = fmaf(p, h, sv);
    }
}

// ---------------------------------------------------------------------------
// Pass 3 (direct loads, R7-verified)
// ---------------------------------------------------------------------------
__global__ __launch_bounds__(256)
void scan_pass3(const bf16* delta, const bf16* __restrict__ xms,
                const bf16* __restrict__ dblb, const float* __restrict__ A_log,
                const float* __restrict__ Hinit, const float* __restrict__ Dp,
                const bf16* __restrict__ zb, bf16* Y, int L)
{
    const int NC = L / CHUNK;
    const int c = blockIdx.x % NC;
    const int b = blockIdx.x / NC;
    const int d = blockIdx.y * 256 + threadIdx.x;

    __shared__ float Bsh[CHUNK][DSTATE];
    __shared__ float Csh[CHUNK][DSTATE];
#pragma unroll
    for (int it = 0; it < CHUNK * DSTATE / 256; ++it) {
        int idx = threadIdx.x + it * 256;
        int t = idx >> 4, s = idx & 15;
        size_t base = (size_t)(b * L + c * CHUNK + t) * 64;
        Bsh[t][s] = bf2f(dblb[base + 32 + s]);
        Csh[t][s] = bf2f(dblb[base + 48 + s]);
    }
    __syncthreads();

    float As_[DSTATE];
    const bool fastA = load_A(A_log, d, As_);

    float h[DSTATE];
#pragma unroll
    for (int s = 0; s < DSTATE; ++s)
        h[s] = Hinit[((size_t)(b * NC + c) * DSTATE + s) * 1024 + d];

    const float Dd = Dp[d];

    if (fastA) {
        for (int t = 0; t < CHUNK; ++t) {
            size_t row = (size_t)(b * L + c * CHUNK + t);
            float de = bf2f(delta[row * 1024 + d]);
            float x  = bf2f(xms[row * 1024 + d]);
            float dx = de * x;
            float r = __expf(-de);
            float a = r;
            float y0 = 0.f, y1 = 0.f;
#pragma unroll
            for (int s = 0; s < DSTATE; s += 2) {
                h[s] = fmaf(a, h[s], dx * Bsh[t][s]);
                y0 = fmaf(h[s], Csh[t][s], y0);
                a *= r;
                h[s+1] = fmaf(a, h[s+1], dx * Bsh[t][s+1]);
                y1 = fmaf(h[s+1], Csh[t][s+1], y1);
                a *= r;
            }
            float y = y0 + y1 + x * Dd;
            float z = bf2f(zb[row * 1024 + d]);
            Y[row * 1024 + d] = f2bf(y * (z * sigmoidf_(z)));
        }
    } else {
        for (int t = 0; t < CHUNK; ++t) {
            size_t row = (size_t)(b * L + c * CHUNK + t);
            float de = bf2f(delta[row * 1024 + d]);
            float x  = bf2f(xms[row * 1024 + d]);
            float dx = de * x;
            float y0 = 0.f, y1 = 0.f;
#pragma unroll
            for (int s = 0; s < DSTATE; s += 2) {
                float dA0 = __expf(de * As_[s]);
                float dA1 = __expf(de * As_[s+1]);
                h[s] = fmaf(dA0, h[s], dx * Bsh[t][s]);
                y0 = fmaf(h[s], Csh[t][s], y0);
                h[s+1] = fmaf(dA1, h[s+1], dx * Bsh[t][s+1]);
                y1 = fmaf(h[s+1], Csh[t][s+1], y1);
            }
            float y = y0 + y1 + x * Dd;
            float z = bf2f(zb[row * 1024 + d]);
            Y[row * 1024 + d] = f2bf(y * (z * sigmoidf_(z)));
        }
    }
}

// ---------------------------------------------------------------------------

extern "C" void kernel_launch(void* const* d_in, const int* in_sizes, int n_in,
                              void* d_out, int out_size, void* d_ws, size_t ws_size,
                              hipStream_t stream)
{
    (void)in_sizes; (void)n_in; (void)out_size;

    const float* x         = (const float*)d_in[0];
    const float* enc_w1    = (const float*)d_in[1];
    const float* enc_b1    = (const float*)d_in[2];
    const float* enc_w2    = (const float*)d_in[3];
    const float* enc_b2    = (const float*)d_in[4];
    const float* in_proj_w = (const float*)d_in[5];
    const float* conv_w    = (const float*)d_in[6];
    const float* conv_b    = (const float*)d_in[7];
    const float* x_proj_w  = (const float*)d_in[8];
    const float* dt_proj_w = (const float*)d_in[9];
    const float* dt_proj_b = (const float*)d_in[10];
    const float* A_log     = (const float*)d_in[11];
    const float* D_param   = (const float*)d_in[12];
    const float* out_proj_w= (const float*)d_in[13];
    const float* dec_w1    = (const float*)d_in[14];
    const float* dec_b1    = (const float*)d_in[15];
    const float* dec_w2    = (const float*)d_in[16];
    const float* dec_b2    = (const float*)d_in[17];
    float* out = (float*)d_out;

    const int L = 2048, NC = L / CHUNK;   // NC = 64

    // ---- bf16 fixed region (weights + x) ----
    bf16* wb = (bf16*)d_ws;
    size_t off = 0;
    bf16* w_enc1 = wb + off; off += 16384;
    bf16* w_enc2 = wb + off; off += 131072;
    bf16* w_inpj = wb + off; off += 1048576;
    bf16* w_xprj = wb + off; off += 65536;
    bf16* w_dtpj = wb + off; off += 32768;
    bf16* w_outp = wb + off; off += 524288;
    bf16* w_dec1 = wb + off; off += 131072;
    bf16* w_dec2 = wb + off; off += 16384;
    bf16* xbf    = wb + off; off += 1048576;
    const size_t fixedB = off * 2;         // 6,029,312 B

    const size_t PER_ROW = 11904;
    int SPLIT = 8;
    if      (fixedB + (size_t)16384 * PER_ROW <= ws_size) SPLIT = 1;
    else if (fixedB + (size_t) 8192 * PER_ROW <= ws_size) SPLIT = 2;  // 103.5 MB (R7-proven fit)
    else if (fixedB + (size_t) 4096 * PER_ROW <= ws_size) SPLIT = 4;

    const int NB = 8 / SPLIT;
    const int MR = NB * L;

    char* pb = (char*)d_ws + fixedB;
    bf16* hbf   = (bf16*)pb;                     // MR x 256
    bf16* ubf   = hbf   + (size_t)MR * 256;      // MR x 512 (u, o)
    bf16* slot3 = ubf   + (size_t)MR * 512;      // MR x 1024 (xm_raw -> delta -> y)
    bf16* zbf   = slot3 + (size_t)MR * 1024;     // MR x 1024
    bf16* xms   = zbf   + (size_t)MR * 1024;     // MR x 1024
    bf16* dblb  = xms   + (size_t)MR * 1024;     // MR x 64
    float* Pf   = (float*)(dblb + (size_t)MR * 64);  // MR x 512 f32 (-> Hinit)
    float* Sf   = Pf + (size_t)MR * 512;             // MR x 512 f32

    CastJobs J;
    J.src[0] = enc_w1;     J.dst[0] = w_enc1; J.n[0] = 16384;
    J.src[1] = enc_w2;     J.dst[1] = w_enc2; J.n[1] = 131072;
    J.src[2] = in_proj_w;  J.dst[2] = w_inpj; J.n[2] = 1048576;
    J.src[3] = x_proj_w;   J.dst[3] = w_xprj; J.n[3] = 65536;
    J.src[4] = dt_proj_w;  J.dst[4] = w_dtpj; J.n[4] = 32768;
    J.src[5] = out_proj_w; J.dst[5] = w_outp; J.n[5] = 524288;
    J.src[6] = dec_w1;     J.dst[6] = w_dec1; J.n[6] = 131072;
    J.src[7] = dec_w2;     J.dst[7] = w_dec2; J.n[7] = 16384;
    J.src[8] = x;          J.dst[8] = xbf;    J.n[8] = 1048576;
    cast_bf16_kernel<<<dim3(128, 9), 256, 0, stream>>>(J);

    dim3 blk(256);
    for (int p = 0; p < SPLIT; ++p) {
        const bf16* xp  = xbf + (size_t)p * MR * 64;
        float*     outp = out + (size_t)p * MR * 64;

        // enc1: relu(x @ enc_w1^T + b1) -> h (MR x 256), K=64   [BM=64: 2x grid]
        gemm_mfma<64,128,1,1><<<dim3(2, MR/64), blk, 0, stream>>>(
            xp, 64, w_enc1, 64, enc_b1, hbf, 256, 64);
        // enc2: u = h @ enc_w2^T + b2 (MR x 512), K=256
        gemm_mfma<128,128,0,1><<<dim3(4, MR/128), blk, 0, stream>>>(
            hbf, 256, w_enc2, 256, enc_b2, ubf, 512, 256);
        // in_proj xm half -> slot3, K=512
        gemm_mfma<128,128,0,1><<<dim3(8, MR/128), blk, 0, stream>>>(
            ubf, 512, w_inpj, 512, nullptr, slot3, 1024, 512);
        // in_proj z half -> zbf
        gemm_mfma<128,128,0,1><<<dim3(8, MR/128), blk, 0, stream>>>(
            ubf, 512, w_inpj + (size_t)1024 * 512, 512, nullptr, zbf, 1024, 512);
        // conv + silu: slot3 -> xms
        conv_silu_kernel<<<dim3(NB * (L/32), 4), blk, 0, stream>>>(
            slot3, conv_w, conv_b, xms, L);
        // x_proj: dbl = xms @ x_proj_w^T (MR x 64), K=1024      [BM=64]
        gemm_mfma<64,64,0,1><<<dim3(1, MR/64), blk, 0, stream>>>(
            xms, 1024, w_xprj, 1024, nullptr, dblb, 64, 1024);
        // dt_proj + softplus: delta -> slot3, K=32
        gemm_mfma<128,128,2,1><<<dim3(8, MR/128), blk, 0, stream>>>(
            dblb, 64, w_dtpj, 32, dt_proj_b, slot3, 1024, 32);
        // selective scan (CHUNK=32, NC=64)
        scan_pass1<<<dim3(NB * NC, 4), blk, 0, stream>>>(
            slot3, xms, dblb, A_log, Pf, Sf, L);
        scan_pass2<<<dim3(NB * 64), blk, 0, stream>>>(Pf, Sf, Pf, NC);
        scan_pass3<<<dim3(NB * NC, 4), blk, 0, stream>>>(
            slot3, xms, dblb, A_log, Pf, D_param, zbf, slot3 /*y*/, L);
        // out_proj: o = y @ out_proj_w^T (MR x 512), K=1024
        gemm_mfma<128,128,0,1><<<dim3(4, MR/128), blk, 0, stream>>>(
            slot3, 1024, w_outp, 1024, nullptr, ubf, 512, 1024);
        // dec1: relu(o @ dec_w1^T + b1) (MR x 256), K=512       [BM=64: 2x grid]
        gemm_mfma<64,128,1,1><<<dim3(2, MR/64), blk, 0, stream>>>(
            ubf, 512, w_dec1, 512, dec_b1, hbf, 256, 512);
        // dec2: out = h2 @ dec_w2^T + b2 (MR x 64 f32), K=256   [BM=64]
        gemm_mfma<64,64,0,0><<<dim3(1, MR/64), blk, 0, stream>>>(
            hbf, 256, w_dec2, 256, dec_b2, outp, 64, 256);
    }
}

// Round 9
// 368.669 us; speedup vs baseline: 1.7653x; 1.0043x over previous
//
#include <hip/hip_runtime.h>
#include <hip/hip_bf16.h>

typedef __attribute__((ext_vector_type(8))) short bf16x8;
typedef __attribute__((ext_vector_type(4))) float f32x4;
typedef __attribute__((ext_vector_type(4))) unsigned short u16x4;
typedef __hip_bfloat16 bf16;

#define DEV __device__ __forceinline__
DEV float sigmoidf_(float x) { return 1.0f / (1.0f + __expf(-x)); }
DEV float bf2f(bf16 v) { return __bfloat162float(v); }
DEV bf16  f2bf(float v) { return __float2bfloat16(v); }

typedef const __attribute__((address_space(1))) void* gptr_t;
typedef __attribute__((address_space(3))) void* lptr_t;

template<int N> DEV void waitcnt_vm() {
    if constexpr (N == 0) asm volatile("s_waitcnt vmcnt(0)" ::: "memory");
    else if constexpr (N == 2) asm volatile("s_waitcnt vmcnt(2)" ::: "memory");
    else if constexpr (N == 3) asm volatile("s_waitcnt vmcnt(3)" ::: "memory");
    else asm volatile("s_waitcnt vmcnt(4)" ::: "memory");
}

// ---------------------------------------------------------------------------
// bf16 MFMA GEMM v2 (R8-verified): C = act(A @ W^T + bias)
// 2-phase dbuf global_load_lds, counted vmcnt, coalesced LDS epilogue.
// ---------------------------------------------------------------------------
template<int BM, int BN, int ACT, int OUTBF>
__global__ __launch_bounds__(256)
void gemm_mfma(const bf16* __restrict__ A, int lda,
               const bf16* __restrict__ W, int ldw,
               const float* __restrict__ bias,
               void* __restrict__ Cp, int ldc, int K)
{
    constexpr int BK = 32;
    constexpr int WMS = BM / 2, WNS = BN / 2;
    constexpr int FM = WMS / 16, FN = WNS / 16;
    constexpr int AITER = (BM * BK) / (256 * 8);
    constexpr int BITER = (BN * BK) / (256 * 8);
    constexpr int NLD = AITER + BITER;
    constexpr int BUFB = (BM + BN) * BK * 2;

    __shared__ __align__(16) char smem[2 * BUFB];

    const int tid = threadIdx.x;
    const int lane = tid & 63;
    const int wid = tid >> 6;
    const int wm = wid >> 1, wn = wid & 1;
    const long m0 = (long)blockIdx.y * BM;
    const long n0 = (long)blockIdx.x * BN;

    f32x4 acc[FM][FN] = {};

    long aoff[AITER];
#pragma unroll
    for (int it = 0; it < AITER; ++it) {
        int q = it * 256 + tid;
        int r = q >> 2;
        aoff[it] = (long)(m0 + r) * lda * 2 + (((q & 3) * 16) ^ ((r & 3) << 4));
    }
    long boff[BITER];
#pragma unroll
    for (int it = 0; it < BITER; ++it) {
        int q = it * 256 + tid;
        int r = q >> 2;
        boff[it] = (long)(n0 + r) * ldw * 2 + (((q & 3) * 16) ^ ((r & 3) << 4));
    }

    const char* Ac = (const char*)A;
    const char* Wc = (const char*)W;

#pragma unroll
    for (int it = 0; it < AITER; ++it)
        __builtin_amdgcn_global_load_lds((gptr_t)(Ac + aoff[it]),
            (lptr_t)(smem + (it * 256 + wid * 64) * 16), 16, 0, 0);
#pragma unroll
    for (int it = 0; it < BITER; ++it)
        __builtin_amdgcn_global_load_lds((gptr_t)(Wc + boff[it]),
            (lptr_t)(smem + BM * BK * 2 + (it * 256 + wid * 64) * 16), 16, 0, 0);

    const int NK = K / BK;
    const int fr = lane & 15, fq = lane >> 4;
    const int swz = (fr & 3) << 4;
    int cur = 0;

    for (int ks = 0; ks < NK; ++ks) {
        if (ks + 1 < NK) {
            const long k2 = (long)(ks + 1) * BK * 2;
            char* dst = smem + (cur ^ 1) * BUFB;
#pragma unroll
            for (int it = 0; it < AITER; ++it)
                __builtin_amdgcn_global_load_lds((gptr_t)(Ac + aoff[it] + k2),
                    (lptr_t)(dst + (it * 256 + wid * 64) * 16), 16, 0, 0);
#pragma unroll
            for (int it = 0; it < BITER; ++it)
                __builtin_amdgcn_global_load_lds((gptr_t)(Wc + boff[it] + k2),
                    (lptr_t)(dst + BM * BK * 2 + (it * 256 + wid * 64) * 16), 16, 0, 0);
            waitcnt_vm<NLD>();
        } else {
            waitcnt_vm<0>();
        }
        __builtin_amdgcn_s_barrier();
        __builtin_amdgcn_sched_barrier(0);

        const char* base = smem + cur * BUFB;
        bf16x8 av[FM], bv[FN];
#pragma unroll
        for (int fm = 0; fm < FM; ++fm) {
            int ra = wm * WMS + fm * 16 + fr;
            av[fm] = *(const bf16x8*)(base + ra * 64 + ((fq * 16) ^ swz));
        }
#pragma unroll
        for (int fn = 0; fn < FN; ++fn) {
            int rb = wn * WNS + fn * 16 + fr;
            bv[fn] = *(const bf16x8*)(base + BM * BK * 2 + rb * 64 + ((fq * 16) ^ swz));
        }
#pragma unroll
        for (int fm = 0; fm < FM; ++fm)
#pragma unroll
            for (int fn = 0; fn < FN; ++fn)
                acc[fm][fn] = __builtin_amdgcn_mfma_f32_16x16x32_bf16(
                    av[fm], bv[fn], acc[fm][fn], 0, 0, 0);

        asm volatile("s_waitcnt lgkmcnt(0)" ::: "memory");
        __builtin_amdgcn_sched_barrier(0);
        __builtin_amdgcn_s_barrier();
        cur ^= 1;
    }

    float bcol[FN];
#pragma unroll
    for (int fn = 0; fn < FN; ++fn)
        bcol[fn] = bias ? bias[n0 + wn * WNS + fn * 16 + fr] : 0.0f;

    if constexpr (OUTBF) {
        constexpr int CST = BN + 8;
        bf16* ct = (bf16*)smem;
        for (int mh = 0; mh < BM / 64; ++mh) {
            __syncthreads();
            if (BM == 64 || wm == mh) {
#pragma unroll
                for (int fm = 0; fm < FM; ++fm) {
                    int lr0 = (BM == 64 ? wm * WMS : 0) + fm * 16 + fq * 4;
#pragma unroll
                    for (int fn = 0; fn < FN; ++fn) {
                        int lc = wn * WNS + fn * 16 + fr;
#pragma unroll
                        for (int r = 0; r < 4; ++r) {
                            float v = acc[fm][fn][r] + bcol[fn];
                            if (ACT == 1) v = fmaxf(v, 0.0f);
                            else if (ACT == 2)
                                v = fmaxf(v, 0.0f) + __logf(1.0f + __expf(-fabsf(v)));
                            ct[(lr0 + r) * CST + lc] = f2bf(v);
                        }
                    }
                }
            }
            __syncthreads();
            constexpr int GPR = BN / 8;
#pragma unroll
            for (int it = 0; it < (64 * GPR) / 256; ++it) {
                int idx = it * 256 + tid;
                int row = idx / GPR, cg = idx % GPR;
                bf16x8 v8 = *(const bf16x8*)&ct[row * CST + cg * 8];
                *(bf16x8*)((bf16*)Cp + (size_t)(m0 + mh * 64 + row) * ldc
                           + n0 + cg * 8) = v8;
            }
        }
    } else {
#pragma unroll
        for (int fn = 0; fn < FN; ++fn) {
            long col = n0 + wn * WNS + fn * 16 + fr;
#pragma unroll
            for (int fm = 0; fm < FM; ++fm) {
                long row0 = m0 + wm * WMS + fm * 16 + fq * 4;
#pragma unroll
                for (int r = 0; r < 4; ++r) {
                    float v = acc[fm][fn][r] + bcol[fn];
                    if (ACT == 1) v = fmaxf(v, 0.0f);
                    ((float*)Cp)[(size_t)(row0 + r) * ldc + col] = v;
                }
            }
        }
    }
}

// ---------------------------------------------------------------------------
struct CastJobs {
    const float* src[9];
    bf16* dst[9];
    int n[9];
};

__global__ __launch_bounds__(256)
void cast_bf16_kernel(CastJobs J)
{
    const int seg = blockIdx.y;
    const f32x4* s = (const f32x4*)J.src[seg];
    u16x4* d = (u16x4*)J.dst[seg];
    const int n4 = J.n[seg] >> 2;
    for (int i = blockIdx.x * 256 + threadIdx.x; i < n4; i += gridDim.x * 256) {
        f32x4 v = s[i];
        u16x4 o;
#pragma unroll
        for (int j = 0; j < 4; ++j) {
            bf16 b = f2bf(v[j]);
            o[j] = *(unsigned short*)&b;
        }
        d[i] = o;
    }
}

#define DSTATE 16
#define CHUNK 16      // scan chunk (NC = L/16 = 128): 2x waves vs R8

// ---------------------------------------------------------------------------
// Depthwise causal conv (k=4) + bias + silu. bf16 in/out, f32 math.
// ---------------------------------------------------------------------------
__global__ __launch_bounds__(256)
void conv_silu_kernel(const bf16* __restrict__ xmr, const float* __restrict__ cw,
                      const float* __restrict__ cb, bf16* __restrict__ xms, int L)
{
    const int NCc = L / 32;
    const int c = blockIdx.x % NCc;
    const int b = blockIdx.x / NCc;
    const int d = blockIdx.y * 256 + threadIdx.x;

    const float w0 = cw[d * 4 + 0], w1 = cw[d * 4 + 1];
    const float w2 = cw[d * 4 + 2], w3 = cw[d * 4 + 3];
    const float bb = cb[d];

    const int t0 = c * 32;
    float x0 = 0.f, x1 = 0.f, x2 = 0.f;
    if (t0 >= 3) {
        x0 = bf2f(xmr[(size_t)(b * L + t0 - 3) * 1024 + d]);
        x1 = bf2f(xmr[(size_t)(b * L + t0 - 2) * 1024 + d]);
        x2 = bf2f(xmr[(size_t)(b * L + t0 - 1) * 1024 + d]);
    }
    for (int t = t0; t < t0 + 32; ++t) {
        float x3 = bf2f(xmr[(size_t)(b * L + t) * 1024 + d]);
        float v = fmaf(w0, x0, fmaf(w1, x1, fmaf(w2, x2, fmaf(w3, x3, bb))));
        xms[(size_t)(b * L + t) * 1024 + d] = f2bf(v * sigmoidf_(v));
        x0 = x1; x1 = x2; x2 = x3;
    }
}

// ---------------------------------------------------------------------------
// A-matrix helper: detect A_s == -(s+1) (A_log = log(arange(1..16)) broadcast).
// ---------------------------------------------------------------------------
DEV bool load_A(const float* __restrict__ A_log, int d, float* As_)
{
    bool fastA = true;
#pragma unroll
    for (int s = 0; s < DSTATE; ++s) {
        As_[s] = -__expf(A_log[(size_t)d * DSTATE + s]);
        fastA = fastA && (fabsf(As_[s] + (float)(s + 1)) <= 1e-4f * (s + 1));
    }
    return fastA;
}

// Shallow power table: a[s] = r^(s+1), 15 muls at depth 5 (vs serial depth 16).
DEV void powa(float r, float* a)
{
    float r2 = r * r;
    float r4 = r2 * r2;
    float r8 = r4 * r4;
    float r3 = r2 * r;
    a[0] = r;       a[1] = r2;      a[2] = r3;      a[3] = r4;
    a[4] = r4 * r;  a[5] = r4 * r2; a[6] = r4 * r3; a[7] = r8;
    a[8] = r8 * r;  a[9] = r8 * r2; a[10] = r8 * r3; a[11] = r8 * r4;
    a[12] = a[11] * r; a[13] = a[11] * r2; a[14] = a[11] * r3; a[15] = r8 * r8;
}

// ---------------------------------------------------------------------------
// Scan pass 1: per chunk of 16 t's, P = prod(dA), S = local scan end (bf16).
// Register prefetch of next t's delta/xms. grid: (NB*NC, 4), block 256.
// ---------------------------------------------------------------------------
__global__ __launch_bounds__(256)
void scan_pass1(const bf16* __restrict__ delta, const bf16* __restrict__ xms,
                const bf16* __restrict__ dblb, const float* __restrict__ A_log,
                bf16* __restrict__ P, bf16* __restrict__ S, int L)
{
    const int NC = L / CHUNK;
    const int c = blockIdx.x % NC;
    const int b = blockIdx.x / NC;
    const int d = blockIdx.y * 256 + threadIdx.x;

    __shared__ float Bsh[CHUNK][DSTATE];
    {
        int t = threadIdx.x >> 4, s = threadIdx.x & 15;
        Bsh[t][s] = bf2f(dblb[(size_t)(b * L + c * CHUNK + t) * 64 + 32 + s]);
    }
    __syncthreads();

    float As_[DSTATE];
    const bool fastA = load_A(A_log, d, As_);

    float h[DSTATE], p[DSTATE];
#pragma unroll
    for (int s = 0; s < DSTATE; ++s) { h[s] = 0.f; p[s] = 1.f; }

    const size_t rb = (size_t)(b * L + c * CHUNK);
    float de_n = bf2f(delta[rb * 1024 + d]);
    float x_n  = bf2f(xms[rb * 1024 + d]);

    if (fastA) {
#pragma unroll 4
        for (int t = 0; t < CHUNK; ++t) {
            float de = de_n, x = x_n;
            if (t + 1 < CHUNK) {
                de_n = bf2f(delta[(rb + t + 1) * 1024 + d]);
                x_n  = bf2f(xms[(rb + t + 1) * 1024 + d]);
            }
            float dx = de * x;
            float r = __expf(-de);
            float a[DSTATE];
            powa(r, a);
#pragma unroll
            for (int s = 0; s < DSTATE; ++s) {
                h[s] = fmaf(a[s], h[s], dx * Bsh[t][s]);
                p[s] *= a[s];
            }
        }
    } else {
#pragma unroll 4
        for (int t = 0; t < CHUNK; ++t) {
            float de = de_n, x = x_n;
            if (t + 1 < CHUNK) {
                de_n = bf2f(delta[(rb + t + 1) * 1024 + d]);
                x_n  = bf2f(xms[(rb + t + 1) * 1024 + d]);
            }
            float dx = de * x;
#pragma unroll
            for (int s = 0; s < DSTATE; ++s) {
                float dA = __expf(de * As_[s]);
                h[s] = fmaf(dA, h[s], dx * Bsh[t][s]);
                p[s] *= dA;
            }
        }
    }
#pragma unroll
    for (int s = 0; s < DSTATE; ++s) {
        size_t o = ((size_t)(b * NC + c) * DSTATE + s) * 1024 + d;
        P[o] = f2bf(p[s]);
        S[o] = f2bf(h[s]);
    }
}

// ---------------------------------------------------------------------------
// Pass 2: serial combine over NC=128 chunks, 8-deep batched loads.
// Hinit in place of P (all batch loads precede batch stores).
// grid: NB*64 blocks of 256.
// ---------------------------------------------------------------------------
__global__ __launch_bounds__(256)
void scan_pass2(const bf16* P, const bf16* __restrict__ S, bf16* Hinit, int NC)
{
    int g = blockIdx.x * 256 + threadIdx.x;
    int d = g & 1023;
    int s = (g >> 10) & 15;
    int b = g >> 14;
    const size_t cs = (size_t)DSTATE * 1024;
    size_t o = ((size_t)(b * NC) * DSTATE + s) * 1024 + d;
    float h = 0.f;
    for (int c0 = 0; c0 < NC; c0 += 8) {
        float pv[8], sv[8];
#pragma unroll
        for (int j = 0; j < 8; ++j) {
            pv[j] = bf2f(P[o + j * cs]);
            sv[j] = bf2f(S[o + j * cs]);
        }
#pragma unroll
        for (int j = 0; j < 8; ++j) {
            Hinit[o + j * cs] = f2bf(h);
            h = fmaf(pv[j], h, sv[j]);
        }
        o += 8 * cs;
    }
}

// ---------------------------------------------------------------------------
// Pass 3: recompute local scan from Hinit (bf16), y = (sum h*C + x*D)*silu(z).
// Register prefetch; Y aliases delta (load t+1 precedes store t).
// ---------------------------------------------------------------------------
__global__ __launch_bounds__(256)
void scan_pass3(const bf16* delta, const bf16* __restrict__ xms,
                const bf16* __restrict__ dblb, const float* __restrict__ A_log,
                const bf16* __restrict__ Hinit, const float* __restrict__ Dp,
                const bf16* __restrict__ zb, bf16* Y, int L)
{
    const int NC = L / CHUNK;
    const int c = blockIdx.x % NC;
    const int b = blockIdx.x / NC;
    const int d = blockIdx.y * 256 + threadIdx.x;

    __shared__ float Bsh[CHUNK][DSTATE];
    __shared__ float Csh[CHUNK][DSTATE];
    {
        int t = threadIdx.x >> 4, s = threadIdx.x & 15;
        size_t base = (size_t)(b * L + c * CHUNK + t) * 64;
        Bsh[t][s] = bf2f(dblb[base + 32 + s]);
        Csh[t][s] = bf2f(dblb[base + 48 + s]);
    }
    __syncthreads();

    float As_[DSTATE];
    const bool fastA = load_A(A_log, d, As_);

    float h[DSTATE];
#pragma unroll
    for (int s = 0; s < DSTATE; ++s)
        h[s] = bf2f(Hinit[((size_t)(b * NC + c) * DSTATE + s) * 1024 + d]);

    const float Dd = Dp[d];
    const size_t rb = (size_t)(b * L + c * CHUNK);
    float de_n = bf2f(delta[rb * 1024 + d]);
    float x_n  = bf2f(xms[rb * 1024 + d]);
    float z_n  = bf2f(zb[rb * 1024 + d]);

    if (fastA) {
#pragma unroll 4
        for (int t = 0; t < CHUNK; ++t) {
            float de = de_n, x = x_n, z = z_n;
            if (t + 1 < CHUNK) {
                de_n = bf2f(delta[(rb + t + 1) * 1024 + d]);
                x_n  = bf2f(xms[(rb + t + 1) * 1024 + d]);
                z_n  = bf2f(zb[(rb + t + 1) * 1024 + d]);
            }
            float dx = de * x;
            float r = __expf(-de);
            float a[DSTATE];
            powa(r, a);
            float y0 = 0.f, y1 = 0.f;
#pragma unroll
            for (int s = 0; s < DSTATE; s += 2) {
                h[s] = fmaf(a[s], h[s], dx * Bsh[t][s]);
                y0 = fmaf(h[s], Csh[t][s], y0);
                h[s+1] = fmaf(a[s+1], h[s+1], dx * Bsh[t][s+1]);
                y1 = fmaf(h[s+1], Csh[t][s+1], y1);
            }
            float y = y0 + y1 + x * Dd;
            Y[(rb + t) * 1024 + d] = f2bf(y * (z * sigmoidf_(z)));
        }
    } else {
#pragma unroll 4
        for (int t = 0; t < CHUNK; ++t) {
            float de = de_n, x = x_n, z = z_n;
            if (t + 1 < CHUNK) {
                de_n = bf2f(delta[(rb + t + 1) * 1024 + d]);
                x_n  = bf2f(xms[(rb + t + 1) * 1024 + d]);
                z_n  = bf2f(zb[(rb + t + 1) * 1024 + d]);
            }
            float dx = de * x;
            float y0 = 0.f, y1 = 0.f;
#pragma unroll
            for (int s = 0; s < DSTATE; s += 2) {
                float dA0 = __expf(de * As_[s]);
                float dA1 = __expf(de * As_[s+1]);
                h[s] = fmaf(dA0, h[s], dx * Bsh[t][s]);
                y0 = fmaf(h[s], Csh[t][s], y0);
                h[s+1] = fmaf(dA1, h[s+1], dx * Bsh[t][s+1]);
                y1 = fmaf(h[s+1], Csh[t][s+1], y1);
            }
            float y = y0 + y1 + x * Dd;
            Y[(rb + t) * 1024 + d] = f2bf(y * (z * sigmoidf_(z)));
        }
    }
}

// ---------------------------------------------------------------------------

extern "C" void kernel_launch(void* const* d_in, const int* in_sizes, int n_in,
                              void* d_out, int out_size, void* d_ws, size_t ws_size,
                              hipStream_t stream)
{
    (void)in_sizes; (void)n_in; (void)out_size;

    const float* x         = (const float*)d_in[0];
    const float* enc_w1    = (const float*)d_in[1];
    const float* enc_b1    = (const float*)d_in[2];
    const float* enc_w2    = (const float*)d_in[3];
    const float* enc_b2    = (const float*)d_in[4];
    const float* in_proj_w = (const float*)d_in[5];
    const float* conv_w    = (const float*)d_in[6];
    const float* conv_b    = (const float*)d_in[7];
    const float* x_proj_w  = (const float*)d_in[8];
    const float* dt_proj_w = (const float*)d_in[9];
    const float* dt_proj_b = (const float*)d_in[10];
    const float* A_log     = (const float*)d_in[11];
    const float* D_param   = (const float*)d_in[12];
    const float* out_proj_w= (const float*)d_in[13];
    const float* dec_w1    = (const float*)d_in[14];
    const float* dec_b1    = (const float*)d_in[15];
    const float* dec_w2    = (const float*)d_in[16];
    const float* dec_b2    = (const float*)d_in[17];
    float* out = (float*)d_out;

    const int L = 2048, NC = L / CHUNK;   // NC = 128

    // ---- bf16 fixed region (weights + x) ----
    bf16* wb = (bf16*)d_ws;
    size_t off = 0;
    bf16* w_enc1 = wb + off; off += 16384;
    bf16* w_enc2 = wb + off; off += 131072;
    bf16* w_inpj = wb + off; off += 1048576;
    bf16* w_xprj = wb + off; off += 65536;
    bf16* w_dtpj = wb + off; off += 32768;
    bf16* w_outp = wb + off; off += 524288;
    bf16* w_dec1 = wb + off; off += 131072;
    bf16* w_dec2 = wb + off; off += 16384;
    bf16* xbf    = wb + off; off += 1048576;
    const size_t fixedB = off * 2;         // 6,029,312 B

    // per-row bytes: hbf(512)+ubf(1024)+slot3(2048)+zbf(2048)+xms(2048)
    //               +dblb(128)+Pb(2048 bf16)+Sb(2048 bf16) = 11904 (== R8)
    const size_t PER_ROW = 11904;
    int SPLIT = 8;
    if      (fixedB + (size_t)16384 * PER_ROW <= ws_size) SPLIT = 1;
    else if (fixedB + (size_t) 8192 * PER_ROW <= ws_size) SPLIT = 2;  // 103.5 MB (proven fit)
    else if (fixedB + (size_t) 4096 * PER_ROW <= ws_size) SPLIT = 4;

    const int NB = 8 / SPLIT;
    const int MR = NB * L;

    char* pb = (char*)d_ws + fixedB;
    bf16* hbf   = (bf16*)pb;                     // MR x 256
    bf16* ubf   = hbf   + (size_t)MR * 256;      // MR x 512 (u, o)
    bf16* slot3 = ubf   + (size_t)MR * 512;      // MR x 1024 (xm_raw -> delta -> y)
    bf16* zbf   = slot3 + (size_t)MR * 1024;     // MR x 1024
    bf16* xms   = zbf   + (size_t)MR * 1024;     // MR x 1024
    bf16* dblb  = xms   + (size_t)MR * 1024;     // MR x 64
    bf16* Pb    = dblb  + (size_t)MR * 64;       // MR x 1024 bf16 (-> Hinit)
    bf16* Sb    = Pb    + (size_t)MR * 1024;     // MR x 1024 bf16

    CastJobs J;
    J.src[0] = enc_w1;     J.dst[0] = w_enc1; J.n[0] = 16384;
    J.src[1] = enc_w2;     J.dst[1] = w_enc2; J.n[1] = 131072;
    J.src[2] = in_proj_w;  J.dst[2] = w_inpj; J.n[2] = 1048576;
    J.src[3] = x_proj_w;   J.dst[3] = w_xprj; J.n[3] = 65536;
    J.src[4] = dt_proj_w;  J.dst[4] = w_dtpj; J.n[4] = 32768;
    J.src[5] = out_proj_w; J.dst[5] = w_outp; J.n[5] = 524288;
    J.src[6] = dec_w1;     J.dst[6] = w_dec1; J.n[6] = 131072;
    J.src[7] = dec_w2;     J.dst[7] = w_dec2; J.n[7] = 16384;
    J.src[8] = x;          J.dst[8] = xbf;    J.n[8] = 1048576;
    cast_bf16_kernel<<<dim3(128, 9), 256, 0, stream>>>(J);

    dim3 blk(256);
    for (int p = 0; p < SPLIT; ++p) {
        const bf16* xp  = xbf + (size_t)p * MR * 64;
        float*     outp = out + (size_t)p * MR * 64;

        // enc1: relu(x @ enc_w1^T + b1) -> h (MR x 256), K=64
        gemm_mfma<64,128,1,1><<<dim3(2, MR/64), blk, 0, stream>>>(
            xp, 64, w_enc1, 64, enc_b1, hbf, 256, 64);
        // enc2: u = h @ enc_w2^T + b2 (MR x 512), K=256
        gemm_mfma<128,128,0,1><<<dim3(4, MR/128), blk, 0, stream>>>(
            hbf, 256, w_enc2, 256, enc_b2, ubf, 512, 256);
        // in_proj xm half -> slot3, K=512
        gemm_mfma<128,128,0,1><<<dim3(8, MR/128), blk, 0, stream>>>(
            ubf, 512, w_inpj, 512, nullptr, slot3, 1024, 512);
        // in_proj z half -> zbf
        gemm_mfma<128,128,0,1><<<dim3(8, MR/128), blk, 0, stream>>>(
            ubf, 512, w_inpj + (size_t)1024 * 512, 512, nullptr, zbf, 1024, 512);
        // conv + silu: slot3 -> xms
        conv_silu_kernel<<<dim3(NB * (L/32), 4), blk, 0, stream>>>(
            slot3, conv_w, conv_b, xms, L);
        // x_proj: dbl = xms @ x_proj_w^T (MR x 64), K=1024
        gemm_mfma<64,64,0,1><<<dim3(1, MR/64), blk, 0, stream>>>(
            xms, 1024, w_xprj, 1024, nullptr, dblb, 64, 1024);
        // dt_proj + softplus: delta -> slot3, K=32
        gemm_mfma<128,128,2,1><<<dim3(8, MR/128), blk, 0, stream>>>(
            dblb, 64, w_dtpj, 32, dt_proj_b, slot3, 1024, 32);
        // selective scan (CHUNK=16, NC=128)
        scan_pass1<<<dim3(NB * NC, 4), blk, 0, stream>>>(
            slot3, xms, dblb, A_log, Pb, Sb, L);
        scan_pass2<<<dim3(NB * 64), blk, 0, stream>>>(Pb, Sb, Pb, NC);
        scan_pass3<<<dim3(NB * NC, 4), blk, 0, stream>>>(
            slot3, xms, dblb, A_log, Pb, D_param, zbf, slot3 /*y*/, L);
        // out_proj: o = y @ out_proj_w^T (MR x 512), K=1024
        gemm_mfma<128,128,0,1><<<dim3(4, MR/128), blk, 0, stream>>>(
            slot3, 1024, w_outp, 1024, nullptr, ubf, 512, 1024);
        // dec1: relu(o @ dec_w1^T + b1) (MR x 256), K=512
        gemm_mfma<64,128,1,1><<<dim3(2, MR/64), blk, 0, stream>>>(
            ubf, 512, w_dec1, 512, dec_b1, hbf, 256, 512);
        // dec2: out = h2 @ dec_w2^T + b2 (MR x 64 f32), K=256
        gemm_mfma<64,64,0,0><<<dim3(1, MR/64), blk, 0, stream>>>(
            hbf, 256, w_dec2, 256, dec_b2, outp, 64, 256);
    }
}

// Round 10
// 349.788 us; speedup vs baseline: 1.8606x; 1.0540x over previous
//
#include <hip/hip_runtime.h>
#include <hip/hip_bf16.h>

typedef __attribute__((ext_vector_type(8))) short bf16x8;
typedef __attribute__((ext_vector_type(4))) float f32x4;
typedef __attribute__((ext_vector_type(4))) unsigned short u16x4;
typedef __hip_bfloat16 bf16;

#define DEV __device__ __forceinline__
DEV float bf2f(bf16 v) { return __bfloat162float(v); }
DEV bf16  f2bf(float v) { return __float2bfloat16(v); }
DEV float sigmoidf_(float x) { return __builtin_amdgcn_rcpf(1.0f + __expf(-x)); }

typedef const __attribute__((address_space(1))) void* gptr_t;
typedef __attribute__((address_space(3))) void* lptr_t;

template<int N> DEV void waitcnt_vm() {
    if constexpr (N == 0) asm volatile("s_waitcnt vmcnt(0)" ::: "memory");
    else if constexpr (N == 2) asm volatile("s_waitcnt vmcnt(2)" ::: "memory");
    else if constexpr (N == 3) asm volatile("s_waitcnt vmcnt(3)" ::: "memory");
    else asm volatile("s_waitcnt vmcnt(4)" ::: "memory");
}

// ---------------------------------------------------------------------------
// bf16 MFMA GEMM (R8-verified): C = act(A @ W^T + bias)
// ACT: 0 none, 1 relu, 2 softplus, 3 silu. OUTBF: 1 bf16, 0 f32.
// ---------------------------------------------------------------------------
template<int BM, int BN, int ACT, int OUTBF>
__global__ __launch_bounds__(256)
void gemm_mfma(const bf16* __restrict__ A, int lda,
               const bf16* __restrict__ W, int ldw,
               const float* __restrict__ bias,
               void* __restrict__ Cp, int ldc, int K)
{
    constexpr int BK = 32;
    constexpr int WMS = BM / 2, WNS = BN / 2;
    constexpr int FM = WMS / 16, FN = WNS / 16;
    constexpr int AITER = (BM * BK) / (256 * 8);
    constexpr int BITER = (BN * BK) / (256 * 8);
    constexpr int NLD = AITER + BITER;
    constexpr int BUFB = (BM + BN) * BK * 2;

    __shared__ __align__(16) char smem[2 * BUFB];

    const int tid = threadIdx.x;
    const int lane = tid & 63;
    const int wid = tid >> 6;
    const int wm = wid >> 1, wn = wid & 1;
    const long m0 = (long)blockIdx.y * BM;
    const long n0 = (long)blockIdx.x * BN;

    f32x4 acc[FM][FN] = {};

    long aoff[AITER];
#pragma unroll
    for (int it = 0; it < AITER; ++it) {
        int q = it * 256 + tid;
        int r = q >> 2;
        aoff[it] = (long)(m0 + r) * lda * 2 + (((q & 3) * 16) ^ ((r & 3) << 4));
    }
    long boff[BITER];
#pragma unroll
    for (int it = 0; it < BITER; ++it) {
        int q = it * 256 + tid;
        int r = q >> 2;
        boff[it] = (long)(n0 + r) * ldw * 2 + (((q & 3) * 16) ^ ((r & 3) << 4));
    }

    const char* Ac = (const char*)A;
    const char* Wc = (const char*)W;

#pragma unroll
    for (int it = 0; it < AITER; ++it)
        __builtin_amdgcn_global_load_lds((gptr_t)(Ac + aoff[it]),
            (lptr_t)(smem + (it * 256 + wid * 64) * 16), 16, 0, 0);
#pragma unroll
    for (int it = 0; it < BITER; ++it)
        __builtin_amdgcn_global_load_lds((gptr_t)(Wc + boff[it]),
            (lptr_t)(smem + BM * BK * 2 + (it * 256 + wid * 64) * 16), 16, 0, 0);

    const int NK = K / BK;
    const int fr = lane & 15, fq = lane >> 4;
    const int swz = (fr & 3) << 4;
    int cur = 0;

    for (int ks = 0; ks < NK; ++ks) {
        if (ks + 1 < NK) {
            const long k2 = (long)(ks + 1) * BK * 2;
            char* dst = smem + (cur ^ 1) * BUFB;
#pragma unroll
            for (int it = 0; it < AITER; ++it)
                __builtin_amdgcn_global_load_lds((gptr_t)(Ac + aoff[it] + k2),
                    (lptr_t)(dst + (it * 256 + wid * 64) * 16), 16, 0, 0);
#pragma unroll
            for (int it = 0; it < BITER; ++it)
                __builtin_amdgcn_global_load_lds((gptr_t)(Wc + boff[it] + k2),
                    (lptr_t)(dst + BM * BK * 2 + (it * 256 + wid * 64) * 16), 16, 0, 0);
            waitcnt_vm<NLD>();
        } else {
            waitcnt_vm<0>();
        }
        __builtin_amdgcn_s_barrier();
        __builtin_amdgcn_sched_barrier(0);

        const char* base = smem + cur * BUFB;
        bf16x8 av[FM], bv[FN];
#pragma unroll
        for (int fm = 0; fm < FM; ++fm) {
            int ra = wm * WMS + fm * 16 + fr;
            av[fm] = *(const bf16x8*)(base + ra * 64 + ((fq * 16) ^ swz));
        }
#pragma unroll
        for (int fn = 0; fn < FN; ++fn) {
            int rb = wn * WNS + fn * 16 + fr;
            bv[fn] = *(const bf16x8*)(base + BM * BK * 2 + rb * 64 + ((fq * 16) ^ swz));
        }
#pragma unroll
        for (int fm = 0; fm < FM; ++fm)
#pragma unroll
            for (int fn = 0; fn < FN; ++fn)
                acc[fm][fn] = __builtin_amdgcn_mfma_f32_16x16x32_bf16(
                    av[fm], bv[fn], acc[fm][fn], 0, 0, 0);

        asm volatile("s_waitcnt lgkmcnt(0)" ::: "memory");
        __builtin_amdgcn_sched_barrier(0);
        __builtin_amdgcn_s_barrier();
        cur ^= 1;
    }

    float bcol[FN];
#pragma unroll
    for (int fn = 0; fn < FN; ++fn)
        bcol[fn] = bias ? bias[n0 + wn * WNS + fn * 16 + fr] : 0.0f;

    if constexpr (OUTBF) {
        constexpr int CST = BN + 8;
        bf16* ct = (bf16*)smem;
        for (int mh = 0; mh < BM / 64; ++mh) {
            __syncthreads();
            if (BM == 64 || wm == mh) {
#pragma unroll
                for (int fm = 0; fm < FM; ++fm) {
                    int lr0 = (BM == 64 ? wm * WMS : 0) + fm * 16 + fq * 4;
#pragma unroll
                    for (int fn = 0; fn < FN; ++fn) {
                        int lc = wn * WNS + fn * 16 + fr;
#pragma unroll
                        for (int r = 0; r < 4; ++r) {
                            float v = acc[fm][fn][r] + bcol[fn];
                            if (ACT == 1) v = fmaxf(v, 0.0f);
                            else if (ACT == 2)
                                v = fmaxf(v, 0.0f) + __logf(1.0f + __expf(-fabsf(v)));
                            else if (ACT == 3)
                                v = v * sigmoidf_(v);
                            ct[(lr0 + r) * CST + lc] = f2bf(v);
                        }
                    }
                }
            }
            __syncthreads();
            constexpr int GPR = BN / 8;
#pragma unroll
            for (int it = 0; it < (64 * GPR) / 256; ++it) {
                int idx = it * 256 + tid;
                int row = idx / GPR, cg = idx % GPR;
                bf16x8 v8 = *(const bf16x8*)&ct[row * CST + cg * 8];
                *(bf16x8*)((bf16*)Cp + (size_t)(m0 + mh * 64 + row) * ldc
                           + n0 + cg * 8) = v8;
            }
        }
    } else {
#pragma unroll
        for (int fn = 0; fn < FN; ++fn) {
            long col = n0 + wn * WNS + fn * 16 + fr;
#pragma unroll
            for (int fm = 0; fm < FM; ++fm) {
                long row0 = m0 + wm * WMS + fm * 16 + fq * 4;
#pragma unroll
                for (int r = 0; r < 4; ++r) {
                    float v = acc[fm][fn][r] + bcol[fn];
                    if (ACT == 1) v = fmaxf(v, 0.0f);
                    ((float*)Cp)[(size_t)(row0 + r) * ldc + col] = v;
                }
            }
        }
    }
}

// ---------------------------------------------------------------------------
struct CastJobs {
    const float* src[9];
    bf16* dst[9];
    int n[9];
};

__global__ __launch_bounds__(256)
void cast_bf16_kernel(CastJobs J)
{
    const int seg = blockIdx.y;
    const f32x4* s = (const f32x4*)J.src[seg];
    u16x4* d = (u16x4*)J.dst[seg];
    const int n4 = J.n[seg] >> 2;
    for (int i = blockIdx.x * 256 + threadIdx.x; i < n4; i += gridDim.x * 256) {
        f32x4 v = s[i];
        u16x4 o;
#pragma unroll
        for (int j = 0; j < 4; ++j) {
            bf16 b = f2bf(v[j]);
            o[j] = *(unsigned short*)&b;
        }
        d[i] = o;
    }
}

#define DSTATE 16
#define CHUNK 32      // scan chunk (NC = 64)

// ---------------------------------------------------------------------------
// Depthwise causal conv (k=4) + bias + silu. bf16 in/out, f32 math.
// ---------------------------------------------------------------------------
__global__ __launch_bounds__(256)
void conv_silu_kernel(const bf16* __restrict__ xmr, const float* __restrict__ cw,
                      const float* __restrict__ cb, bf16* __restrict__ xms, int L)
{
    const int NCc = L / 32;
    const int c = blockIdx.x % NCc;
    const int b = blockIdx.x / NCc;
    const int d = blockIdx.y * 256 + threadIdx.x;

    const float w0 = cw[d * 4 + 0], w1 = cw[d * 4 + 1];
    const float w2 = cw[d * 4 + 2], w3 = cw[d * 4 + 3];
    const float bb = cb[d];

    const int t0 = c * 32;
    float x0 = 0.f, x1 = 0.f, x2 = 0.f;
    if (t0 >= 3) {
        x0 = bf2f(xmr[(size_t)(b * L + t0 - 3) * 1024 + d]);
        x1 = bf2f(xmr[(size_t)(b * L + t0 - 2) * 1024 + d]);
        x2 = bf2f(xmr[(size_t)(b * L + t0 - 1) * 1024 + d]);
    }
    for (int t = t0; t < t0 + 32; ++t) {
        float x3 = bf2f(xmr[(size_t)(b * L + t) * 1024 + d]);
        float v = fmaf(w0, x0, fmaf(w1, x1, fmaf(w2, x2, fmaf(w3, x3, bb))));
        xms[(size_t)(b * L + t) * 1024 + d] = f2bf(v * sigmoidf_(v));
        x0 = x1; x1 = x2; x2 = x3;
    }
}

// ---------------------------------------------------------------------------
// A helper: detect A_s == -(s+1) (A_log = log(arange(1..16)) broadcast).
// ---------------------------------------------------------------------------
DEV bool load_A(const float* __restrict__ A_log, int d, float* As_)
{
    bool fastA = true;
#pragma unroll
    for (int s = 0; s < DSTATE; ++s) {
        As_[s] = -__expf(A_log[(size_t)d * DSTATE + s]);
        fastA = fastA && (fabsf(As_[s] + (float)(s + 1)) <= 1e-4f * (s + 1));
    }
    return fastA;
}

// a[s] = r^(s+1), 15 muls, depth 5.
DEV void powa(float r, float* a)
{
    float r2 = r * r;
    float r3 = r2 * r;
    float r4 = r2 * r2;
    float r8 = r4 * r4;
    a[0] = r;       a[1] = r2;      a[2] = r3;      a[3] = r4;
    a[4] = r4 * r;  a[5] = r4 * r2; a[6] = r4 * r3; a[7] = r8;
    a[8] = r8 * r;  a[9] = r8 * r2; a[10] = r8 * r3; a[11] = r8 * r4;
    a[12] = a[11] * r; a[13] = a[11] * r2; a[14] = a[11] * r3; a[15] = r8 * r8;
}

// ---------------------------------------------------------------------------
// Scan pass 1: local scan; writes chunk-end S, P = R_chunk^(s+1) (fastA),
// AND ylocal_t = C_t . hl_t + x_t*D  IN PLACE over xms (read-then-write per
// element by the same thread; blocks own disjoint (c,d) regions).
// ---------------------------------------------------------------------------
__global__ __launch_bounds__(256)
void scan_pass1(const bf16* __restrict__ delta, bf16* xms /* in: xm, out: ylocal */,
                const bf16* __restrict__ dblb, const float* __restrict__ A_log,
                const float* __restrict__ Dp,
                bf16* __restrict__ P, bf16* __restrict__ S, int L)
{
    const int NC = L / CHUNK;
    const int c = blockIdx.x % NC;
    const int b = blockIdx.x / NC;
    const int d = blockIdx.y * 256 + threadIdx.x;

    __shared__ float Bsh[CHUNK][DSTATE];
    __shared__ float Csh[CHUNK][DSTATE];
#pragma unroll
    for (int it = 0; it < CHUNK * DSTATE / 256; ++it) {
        int idx = threadIdx.x + it * 256;
        int t = idx >> 4, s = idx & 15;
        size_t base = (size_t)(b * L + c * CHUNK + t) * 64;
        Bsh[t][s] = bf2f(dblb[base + 32 + s]);
        Csh[t][s] = bf2f(dblb[base + 48 + s]);
    }
    __syncthreads();

    float As_[DSTATE];
    const bool fastA = load_A(A_log, d, As_);
    const float Dd = Dp[d];

    float h[DSTATE];
#pragma unroll
    for (int s = 0; s < DSTATE; ++s) h[s] = 0.f;

    const size_t rb = (size_t)(b * L + c * CHUNK);

    if (fastA) {
        float sumd = 0.f;
        for (int t = 0; t < CHUNK; ++t) {
            size_t g = (rb + t) * 1024 + d;
            float de = bf2f(delta[g]);
            float x  = bf2f(xms[g]);
            float dx = de * x;
            float r = __expf(-de);
            float a[DSTATE];
            powa(r, a);
            sumd += de;
            float yl = x * Dd;
#pragma unroll
            for (int s = 0; s < DSTATE; ++s) {
                h[s] = fmaf(a[s], h[s], dx * Bsh[t][s]);
                yl = fmaf(h[s], Csh[t][s], yl);
            }
            xms[g] = f2bf(yl);
        }
        float Rc = __expf(-sumd);
        float pa[DSTATE];
        powa(Rc, pa);
#pragma unroll
        for (int s = 0; s < DSTATE; ++s) {
            size_t o = ((size_t)(b * NC + c) * DSTATE + s) * 1024 + d;
            P[o] = f2bf(pa[s]);
            S[o] = f2bf(h[s]);
        }
    } else {
        float p[DSTATE];
#pragma unroll
        for (int s = 0; s < DSTATE; ++s) p[s] = 1.f;
        for (int t = 0; t < CHUNK; ++t) {
            size_t g = (rb + t) * 1024 + d;
            float de = bf2f(delta[g]);
            float x  = bf2f(xms[g]);
            float dx = de * x;
            float yl = x * Dd;
#pragma unroll
            for (int s = 0; s < DSTATE; ++s) {
                float dA = __expf(de * As_[s]);
                h[s] = fmaf(dA, h[s], dx * Bsh[t][s]);
                p[s] *= dA;
                yl = fmaf(h[s], Csh[t][s], yl);
            }
            xms[g] = f2bf(yl);
        }
#pragma unroll
        for (int s = 0; s < DSTATE; ++s) {
            size_t o = ((size_t)(b * NC + c) * DSTATE + s) * 1024 + d;
            P[o] = f2bf(p[s]);
            S[o] = f2bf(h[s]);
        }
    }
}

// ---------------------------------------------------------------------------
// Pass 2: serial combine over NC=64 chunks, 8-deep batched, Hinit over P.
// ---------------------------------------------------------------------------
__global__ __launch_bounds__(256)
void scan_pass2(const bf16* P, const bf16* __restrict__ S, bf16* Hinit, int NC)
{
    int g = blockIdx.x * 256 + threadIdx.x;
    int d = g & 1023;
    int s = (g >> 10) & 15;
    int b = g >> 14;
    const size_t cs = (size_t)DSTATE * 1024;
    size_t o = ((size_t)(b * NC) * DSTATE + s) * 1024 + d;
    float h = 0.f;
    for (int c0 = 0; c0 < NC; c0 += 8) {
        float pv[8], sv[8];
#pragma unroll
        for (int j = 0; j < 8; ++j) {
            pv[j] = bf2f(P[o + j * cs]);
            sv[j] = bf2f(S[o + j * cs]);
        }
#pragma unroll
        for (int j = 0; j < 8; ++j) {
            Hinit[o + j * cs] = f2bf(h);
            h = fmaf(pv[j], h, sv[j]);
        }
        o += 8 * cs;
    }
}

// ---------------------------------------------------------------------------
// Pass 3 (correction-only): y_t = ylocal_t + sum_s C_t[s]*w_t[s],
// w_t[s] = h0[s]*R_t^(s+1) maintained multiplicatively. out = y * zs
// (zs pre-silu'd by GEMM ACT=3). Y aliases delta (read-then-write).
// NO h recurrence, no B tile, no xms read.
// ---------------------------------------------------------------------------
__global__ __launch_bounds__(256)
void scan_pass3(const bf16* delta, const bf16* __restrict__ ylocal,
                const bf16* __restrict__ dblb, const float* __restrict__ A_log,
                const bf16* __restrict__ Hinit,
                const bf16* __restrict__ zs, bf16* Y, int L)
{
    const int NC = L / CHUNK;
    const int c = blockIdx.x % NC;
    const int b = blockIdx.x / NC;
    const int d = blockIdx.y * 256 + threadIdx.x;

    __shared__ float Csh[CHUNK][DSTATE];
#pragma unroll
    for (int it = 0; it < CHUNK * DSTATE / 256; ++it) {
        int idx = threadIdx.x + it * 256;
        int t = idx >> 4, s = idx & 15;
        Csh[t][s] = bf2f(dblb[(size_t)(b * L + c * CHUNK + t) * 64 + 48 + s]);
    }
    __syncthreads();

    float As_[DSTATE];
    const bool fastA = load_A(A_log, d, As_);

    float w[DSTATE];
#pragma unroll
    for (int s = 0; s < DSTATE; ++s)
        w[s] = bf2f(Hinit[((size_t)(b * NC + c) * DSTATE + s) * 1024 + d]);

    const size_t rb = (size_t)(b * L + c * CHUNK);

    if (fastA) {
        for (int t = 0; t < CHUNK; ++t) {
            size_t g = (rb + t) * 1024 + d;
            float de = bf2f(delta[g]);
            float yl = bf2f(ylocal[g]);
            float z  = bf2f(zs[g]);
            float r = __expf(-de);
            float a[DSTATE];
            powa(r, a);
            float c0 = 0.f, c1 = 0.f;
#pragma unroll
            for (int s = 0; s < DSTATE; s += 2) {
                w[s] *= a[s];
                c0 = fmaf(w[s], Csh[t][s], c0);
                w[s+1] *= a[s+1];
                c1 = fmaf(w[s+1], Csh[t][s+1], c1);
            }
            Y[g] = f2bf((yl + c0 + c1) * z);
        }
    } else {
        for (int t = 0; t < CHUNK; ++t) {
            size_t g = (rb + t) * 1024 + d;
            float de = bf2f(delta[g]);
            float yl = bf2f(ylocal[g]);
            float z  = bf2f(zs[g]);
            float c0 = 0.f, c1 = 0.f;
#pragma unroll
            for (int s = 0; s < DSTATE; s += 2) {
                w[s]   *= __expf(de * As_[s]);
                c0 = fmaf(w[s], Csh[t][s], c0);
                w[s+1] *= __expf(de * As_[s+1]);
                c1 = fmaf(w[s+1], Csh[t][s+1], c1);
            }
            Y[g] = f2bf((yl + c0 + c1) * z);
        }
    }
}

// ---------------------------------------------------------------------------

extern "C" void kernel_launch(void* const* d_in, const int* in_sizes, int n_in,
                              void* d_out, int out_size, void* d_ws, size_t ws_size,
                              hipStream_t stream)
{
    (void)in_sizes; (void)n_in; (void)out_size;

    const float* x         = (const float*)d_in[0];
    const float* enc_w1    = (const float*)d_in[1];
    const float* enc_b1    = (const float*)d_in[2];
    const float* enc_w2    = (const float*)d_in[3];
    const float* enc_b2    = (const float*)d_in[4];
    const float* in_proj_w = (const float*)d_in[5];
    const float* conv_w    = (const float*)d_in[6];
    const float* conv_b    = (const float*)d_in[7];
    const float* x_proj_w  = (const float*)d_in[8];
    const float* dt_proj_w = (const float*)d_in[9];
    const float* dt_proj_b = (const float*)d_in[10];
    const float* A_log     = (const float*)d_in[11];
    const float* D_param   = (const float*)d_in[12];
    const float* out_proj_w= (const float*)d_in[13];
    const float* dec_w1    = (const float*)d_in[14];
    const float* dec_b1    = (const float*)d_in[15];
    const float* dec_w2    = (const float*)d_in[16];
    const float* dec_b2    = (const float*)d_in[17];
    float* out = (float*)d_out;

    const int L = 2048, NC = L / CHUNK;   // NC = 64

    // ---- bf16 fixed region (weights + x) ----
    bf16* wb = (bf16*)d_ws;
    size_t off = 0;
    bf16* w_enc1 = wb + off; off += 16384;
    bf16* w_enc2 = wb + off; off += 131072;
    bf16* w_inpj = wb + off; off += 1048576;
    bf16* w_xprj = wb + off; off += 65536;
    bf16* w_dtpj = wb + off; off += 32768;
    bf16* w_outp = wb + off; off += 524288;
    bf16* w_dec1 = wb + off; off += 131072;
    bf16* w_dec2 = wb + off; off += 16384;
    bf16* xbf    = wb + off; off += 1048576;
    const size_t fixedB = off * 2;         // 6,029,312 B

    // per-row bytes: hbf(512)+ubf(1024)+slot3(2048)+zbf(2048)+xms(2048)
    //               +dblb(128)+Pb(1024)+Sb(1024) = 9856
    const size_t PER_ROW = 9856;
    int SPLIT = 8;
    if      (fixedB + (size_t)16384 * PER_ROW <= ws_size) SPLIT = 1;  // 167.5 MB
    else if (fixedB + (size_t) 8192 * PER_ROW <= ws_size) SPLIT = 2;  //  86.8 MB (fits: ws>=103.5 proven)
    else if (fixedB + (size_t) 4096 * PER_ROW <= ws_size) SPLIT = 4;

    const int NB = 8 / SPLIT;
    const int MR = NB * L;

    char* pb = (char*)d_ws + fixedB;
    bf16* hbf   = (bf16*)pb;                     // MR x 256
    bf16* ubf   = hbf   + (size_t)MR * 256;      // MR x 512 (u, o)
    bf16* slot3 = ubf   + (size_t)MR * 512;      // MR x 1024 (xm_raw -> delta -> y)
    bf16* zbf   = slot3 + (size_t)MR * 1024;     // MR x 1024 (silu'd z)
    bf16* xms   = zbf   + (size_t)MR * 1024;     // MR x 1024 (xm_silu -> ylocal)
    bf16* dblb  = xms   + (size_t)MR * 1024;     // MR x 64
    bf16* Pb    = dblb  + (size_t)MR * 64;       // MR x 512 bf16 (-> Hinit)
    bf16* Sb    = Pb    + (size_t)MR * 512;      // MR x 512 bf16

    CastJobs J;
    J.src[0] = enc_w1;     J.dst[0] = w_enc1; J.n[0] = 16384;
    J.src[1] = enc_w2;     J.dst[1] = w_enc2; J.n[1] = 131072;
    J.src[2] = in_proj_w;  J.dst[2] = w_inpj; J.n[2] = 1048576;
    J.src[3] = x_proj_w;   J.dst[3] = w_xprj; J.n[3] = 65536;
    J.src[4] = dt_proj_w;  J.dst[4] = w_dtpj; J.n[4] = 32768;
    J.src[5] = out_proj_w; J.dst[5] = w_outp; J.n[5] = 524288;
    J.src[6] = dec_w1;     J.dst[6] = w_dec1; J.n[6] = 131072;
    J.src[7] = dec_w2;     J.dst[7] = w_dec2; J.n[7] = 16384;
    J.src[8] = x;          J.dst[8] = xbf;    J.n[8] = 1048576;
    cast_bf16_kernel<<<dim3(128, 9), 256, 0, stream>>>(J);

    dim3 blk(256);
    for (int p = 0; p < SPLIT; ++p) {
        const bf16* xp  = xbf + (size_t)p * MR * 64;
        float*     outp = out + (size_t)p * MR * 64;

        // enc1: relu(x @ enc_w1^T + b1) -> h (MR x 256), K=64
        gemm_mfma<64,128,1,1><<<dim3(2, MR/64), blk, 0, stream>>>(
            xp, 64, w_enc1, 64, enc_b1, hbf, 256, 64);
        // enc2: u = h @ enc_w2^T + b2 (MR x 512), K=256
        gemm_mfma<128,128,0,1><<<dim3(4, MR/128), blk, 0, stream>>>(
            hbf, 256, w_enc2, 256, enc_b2, ubf, 512, 256);
        // in_proj xm half -> slot3, K=512
        gemm_mfma<128,128,0,1><<<dim3(8, MR/128), blk, 0, stream>>>(
            ubf, 512, w_inpj, 512, nullptr, slot3, 1024, 512);
        // in_proj z half -> zbf, SILU fused (ACT=3)
        gemm_mfma<128,128,3,1><<<dim3(8, MR/128), blk, 0, stream>>>(
            ubf, 512, w_inpj + (size_t)1024 * 512, 512, nullptr, zbf, 1024, 512);
        // conv + silu: slot3 -> xms
        conv_silu_kernel<<<dim3(NB * (L/32), 4), blk, 0, stream>>>(
            slot3, conv_w, conv_b, xms, L);
        // x_proj: dbl = xms @ x_proj_w^T (MR x 64), K=1024
        gemm_mfma<64,64,0,1><<<dim3(1, MR/64), blk, 0, stream>>>(
            xms, 1024, w_xprj, 1024, nullptr, dblb, 64, 1024);
        // dt_proj + softplus: delta -> slot3, K=32
        gemm_mfma<128,128,2,1><<<dim3(8, MR/128), blk, 0, stream>>>(
            dblb, 64, w_dtpj, 32, dt_proj_b, slot3, 1024, 32);
        // scan: pass1 computes ylocal in place over xms + P,S
        scan_pass1<<<dim3(NB * NC, 4), blk, 0, stream>>>(
            slot3, xms, dblb, A_log, D_param, Pb, Sb, L);
        scan_pass2<<<dim3(NB * 64), blk, 0, stream>>>(Pb, Sb, Pb, NC);
        // pass3: correction-only, zs pre-silu'd; Y over slot3
        scan_pass3<<<dim3(NB * NC, 4), blk, 0, stream>>>(
            slot3, xms, dblb, A_log, Pb, zbf, slot3 /*Y*/, L);
        // out_proj: o = y @ out_proj_w^T (MR x 512), K=1024
        gemm_mfma<128,128,0,1><<<dim3(4, MR/128), blk, 0, stream>>>(
            slot3, 1024, w_outp, 1024, nullptr, ubf, 512, 1024);
        // dec1: relu(o @ dec_w1^T + b1) (MR x 256), K=512
        gemm_mfma<64,128,1,1><<<dim3(2, MR/64), blk, 0, stream>>>(
            ubf, 512, w_dec1, 512, dec_b1, hbf, 256, 512);
        // dec2: out = h2 @ dec_w2^T + b2 (MR x 64 f32), K=256
        gemm_mfma<64,64,0,0><<<dim3(1, MR/64), blk, 0, stream>>>(
            hbf, 256, w_dec2, 256, dec_b2, outp, 64, 256);
    }
}